// Round 3
// baseline (2104.821 us; speedup 1.0000x reference)
//
#include <hip/hip_runtime.h>
#include <hip/hip_bf16.h>
#include <math.h>

#define B_  4
#define N_  4096
#define D_  1024
#define H_  16
#define DK_ 64
#define M_  256
#define R_  (B_*N_)          // 16384 rows
#define EPS_ 1e-6f
#define SPLIT_ 8             // N-chunks for KV accumulation

typedef __bf16 bf16;
typedef __bf16 bf16x4 __attribute__((ext_vector_type(4)));
typedef __bf16 bf16x8 __attribute__((ext_vector_type(8)));
typedef float  f32x4  __attribute__((ext_vector_type(4)));

// ---------------------------------------------------------------------------
// split fp32 -> hi/lo bf16 (lo nullable => plain cast)
// ---------------------------------------------------------------------------
__global__ __launch_bounds__(256)
void split_w(const float* __restrict__ w, bf16* __restrict__ hi,
             bf16* __restrict__ lo, int n)
{
    int i = blockIdx.x * 256 + threadIdx.x;
    if (i < n) {
        float v = w[i];
        bf16 h = (bf16)v;
        hi[i] = h;
        if (lo) lo[i] = (bf16)(v - (float)h);
    }
}

__global__ __launch_bounds__(256)
void zero_f32(float* __restrict__ p, int n)
{
    int i = blockIdx.x * 256 + threadIdx.x;
    if (i < n) p[i] = 0.f;
}

// ---------------------------------------------------------------------------
// QKV projection GEMM, fp32-accurate via 3-pass hi/lo bf16 MFMA.
//   C[r][c] = sum_k X[r][k] * W[colbase+c][k] + bqkv[colbase+c]
// X fp32 staged to LDS, split to hi/lo in-register. W pre-split (Whi/Wlo).
// MODE 0 (KV pass, colbase=1024, grid.x=16): gcol<2048 -> Kf fp32, else Vb bf16
// MODE 1 (Q  pass, colbase=0,    grid.x=8):  -> Qf fp32
// ---------------------------------------------------------------------------
template<int MODE>
__global__ __launch_bounds__(256)
void gemm_qkv(const float* __restrict__ X, const bf16* __restrict__ Whi,
              const bf16* __restrict__ Wlo, const float* __restrict__ bqkv,
              float* __restrict__ QKf, bf16* __restrict__ Vb)
{
    __shared__ float sX[128*64];      // 32 KB
    __shared__ bf16  sBh[128*64];     // 16 KB
    __shared__ bf16  sBl[128*64];     // 16 KB
    const int tid  = threadIdx.x;
    const int bm   = blockIdx.y * 128;
    const int bn   = blockIdx.x * 128;
    const int colbase = (MODE == 0) ? D_ : 0;
    const int lane = tid & 63, wave = tid >> 6;
    const int wm   = (wave & 1) * 64, wn = (wave >> 1) * 64;
    const int m16  = lane & 15, quad = lane >> 4;

    f32x4 acc[4][4];
    #pragma unroll
    for (int i = 0; i < 4; ++i)
        #pragma unroll
        for (int j = 0; j < 4; ++j)
            acc[i][j] = (f32x4){0.f, 0.f, 0.f, 0.f};

    for (int k0 = 0; k0 < D_; k0 += 64) {
        __syncthreads();
        // X tile: 128x64 fp32 = 2048 16B segments (16 per row)
        #pragma unroll
        for (int it = 0; it < 8; ++it) {
            int idx = it*256 + tid;
            int row = idx >> 4, seg = idx & 15;
            const float* g = X + (size_t)(bm + row) * D_ + k0 + seg*4;
            __builtin_amdgcn_global_load_lds(
                (const __attribute__((address_space(1))) void*)g,
                (__attribute__((address_space(3))) void*)&sX[idx*4], 16, 0, 0);
        }
        // W hi/lo tiles: 128x64 bf16 = 1024 16B segments each (8 per row)
        #pragma unroll
        for (int it = 0; it < 4; ++it) {
            int idx = it*256 + tid;
            int row = idx >> 3, seg = idx & 7;
            size_t go = (size_t)(colbase + bn + row) * D_ + k0 + seg*8;
            __builtin_amdgcn_global_load_lds(
                (const __attribute__((address_space(1))) void*)(Whi + go),
                (__attribute__((address_space(3))) void*)&sBh[idx*8], 16, 0, 0);
            __builtin_amdgcn_global_load_lds(
                (const __attribute__((address_space(1))) void*)(Wlo + go),
                (__attribute__((address_space(3))) void*)&sBl[idx*8], 16, 0, 0);
        }
        __syncthreads();
        #pragma unroll
        for (int kk = 0; kk < 64; kk += 32) {
            bf16x8 ahi[4], alo[4], bhi[4], blo[4];
            #pragma unroll
            for (int i = 0; i < 4; ++i) {
                const float* p = &sX[(wm + i*16 + m16)*64 + kk + quad*8];
                float4 p0 = *(const float4*)p;
                float4 p1 = *(const float4*)(p + 4);
                float f[8] = {p0.x, p0.y, p0.z, p0.w, p1.x, p1.y, p1.z, p1.w};
                #pragma unroll
                for (int e = 0; e < 8; ++e) {
                    bf16 h = (bf16)f[e];
                    ahi[i][e] = h;
                    alo[i][e] = (bf16)(f[e] - (float)h);
                }
            }
            #pragma unroll
            for (int j = 0; j < 4; ++j) {
                bhi[j] = *(const bf16x8*)&sBh[(wn + j*16 + m16)*64 + kk + quad*8];
                blo[j] = *(const bf16x8*)&sBl[(wn + j*16 + m16)*64 + kk + quad*8];
            }
            #pragma unroll
            for (int i = 0; i < 4; ++i)
                #pragma unroll
                for (int j = 0; j < 4; ++j) {
                    acc[i][j] = __builtin_amdgcn_mfma_f32_16x16x32_bf16(
                        ahi[i], bhi[j], acc[i][j], 0, 0, 0);
                    acc[i][j] = __builtin_amdgcn_mfma_f32_16x16x32_bf16(
                        alo[i], bhi[j], acc[i][j], 0, 0, 0);
                    acc[i][j] = __builtin_amdgcn_mfma_f32_16x16x32_bf16(
                        ahi[i], blo[j], acc[i][j], 0, 0, 0);
                }
        }
    }

    #pragma unroll
    for (int j = 0; j < 4; ++j) {
        int gcol = colbase + bn + wn + j*16 + m16;
        float bv = bqkv[gcol];
        #pragma unroll
        for (int i = 0; i < 4; ++i) {
            int row0 = bm + wm + i*16 + quad*4;
            #pragma unroll
            for (int r = 0; r < 4; ++r) {
                int row = row0 + r;
                float v = acc[i][j][r] + bv;
                if constexpr (MODE == 0) {
                    if (gcol < 2*D_) QKf[(size_t)row * D_ + gcol - D_]   = v;
                    else             Vb [(size_t)row * D_ + gcol - 2*D_] = (bf16)v;
                } else {
                    QKf[(size_t)row * D_ + gcol] = v;
                }
            }
        }
    }
}

// ---------------------------------------------------------------------------
// Output projection: out[r][c] = (mask[r] ? 0 : sum_k ctx[r][k]*Wob[c][k] + bout[c])
// ctx, Wob bf16 (linear path, bf16-safe); out fp32.
// ---------------------------------------------------------------------------
__global__ __launch_bounds__(256)
void gemm_out(const bf16* __restrict__ A, const bf16* __restrict__ W,
              const float* __restrict__ bias, float* __restrict__ C,
              const int* __restrict__ mask)
{
    __shared__ bf16 sA[128*64];
    __shared__ bf16 sB[128*64];
    const int tid  = threadIdx.x;
    const int bm   = blockIdx.y * 128;
    const int bn   = blockIdx.x * 128;
    const int lane = tid & 63, wave = tid >> 6;
    const int wm   = (wave & 1) * 64, wn = (wave >> 1) * 64;
    const int m16  = lane & 15, quad = lane >> 4;

    f32x4 acc[4][4];
    #pragma unroll
    for (int i = 0; i < 4; ++i)
        #pragma unroll
        for (int j = 0; j < 4; ++j)
            acc[i][j] = (f32x4){0.f, 0.f, 0.f, 0.f};

    for (int k0 = 0; k0 < D_; k0 += 64) {
        __syncthreads();
        #pragma unroll
        for (int it = 0; it < 4; ++it) {
            int idx = it*256 + tid;
            int row = idx >> 3, seg = idx & 7;
            const bf16* gA = A + (size_t)(bm + row) * D_ + k0 + seg*8;
            const bf16* gB = W + (size_t)(bn + row) * D_ + k0 + seg*8;
            __builtin_amdgcn_global_load_lds(
                (const __attribute__((address_space(1))) void*)gA,
                (__attribute__((address_space(3))) void*)&sA[idx*8], 16, 0, 0);
            __builtin_amdgcn_global_load_lds(
                (const __attribute__((address_space(1))) void*)gB,
                (__attribute__((address_space(3))) void*)&sB[idx*8], 16, 0, 0);
        }
        __syncthreads();
        #pragma unroll
        for (int kk = 0; kk < 64; kk += 32) {
            bf16x8 af[4], bfr[4];
            #pragma unroll
            for (int i = 0; i < 4; ++i)
                af[i] = *(const bf16x8*)&sA[(wm + i*16 + m16)*64 + kk + quad*8];
            #pragma unroll
            for (int j = 0; j < 4; ++j)
                bfr[j] = *(const bf16x8*)&sB[(wn + j*16 + m16)*64 + kk + quad*8];
            #pragma unroll
            for (int i = 0; i < 4; ++i)
                #pragma unroll
                for (int j = 0; j < 4; ++j)
                    acc[i][j] = __builtin_amdgcn_mfma_f32_16x16x32_bf16(
                        af[i], bfr[j], acc[i][j], 0, 0, 0);
        }
    }

    #pragma unroll
    for (int j = 0; j < 4; ++j) {
        int col = bn + wn + j*16 + m16;
        float bv = bias[col];
        #pragma unroll
        for (int i = 0; i < 4; ++i) {
            int row0 = bm + wm + i*16 + quad*4;
            #pragma unroll
            for (int r = 0; r < 4; ++r) {
                int row = row0 + r;
                float v = acc[i][j][r] + bv;
                if (mask[row] != 0) v = 0.0f;
                C[(size_t)row * D_ + col] = v;
            }
        }
    }
}

// ---------------------------------------------------------------------------
// Kp = exp(K.omega^T - rowmax)/sqrt(M) (PAD keys skipped, block-uniform),
// atomic-accumulate KV[m][d] += Kp[m]*V[d], ksum[m] += Kp[m]. thread = m.
// ---------------------------------------------------------------------------
__global__ __launch_bounds__(256)
void kv_accum(const float* __restrict__ Kf, const bf16* __restrict__ Vb,
              const int* __restrict__ mask, const float* __restrict__ omega,
              float* __restrict__ KV, float* __restrict__ ksum)
{
    const int chunk = blockIdx.x;
    const int h = blockIdx.y, b = blockIdx.z;
    const int tid = threadIdx.x;          // feature index m
    __shared__ float sK[DK_];
    __shared__ float sV[DK_];
    __shared__ float sred[4];

    float om[64];
    {
        const float* op = omega + ((size_t)h * M_ + tid) * DK_;
        #pragma unroll
        for (int i = 0; i < 16; ++i)
            ((float4*)om)[i] = ((const float4*)op)[i];
    }
    float kv[64];
    #pragma unroll
    for (int d = 0; d < 64; ++d) kv[d] = 0.f;
    float ks = 0.f;

    const int n0 = chunk * (N_ / SPLIT_);
    const float inv_sqrt_m = rsqrtf((float)M_ + 1e-6f);

    for (int nn = 0; nn < N_ / SPLIT_; ++nn) {
        int n = n0 + nn;
        if (mask[b*N_ + n] != 0) continue;       // PAD key (block-uniform)
        size_t rowoff = (size_t)(b*N_ + n) * D_ + h*DK_;
        if (tid < 16) {
            ((float4*)sK)[tid] = ((const float4*)(Kf + rowoff))[tid];
        } else if (tid < 32) {
            int t = tid - 16;
            bf16x4 vv = *(const bf16x4*)(Vb + rowoff + t*4);
            ((float4*)sV)[t] = make_float4((float)vv[0], (float)vv[1],
                                           (float)vv[2], (float)vv[3]);
        }
        __syncthreads();
        float proj = 0.f;
        #pragma unroll
        for (int d4 = 0; d4 < 16; ++d4) {
            float4 kk = ((const float4*)sK)[d4];
            proj += om[d4*4+0]*kk.x + om[d4*4+1]*kk.y + om[d4*4+2]*kk.z + om[d4*4+3]*kk.w;
        }
        float mx = proj;
        #pragma unroll
        for (int off = 32; off > 0; off >>= 1) mx = fmaxf(mx, __shfl_xor(mx, off, 64));
        if ((tid & 63) == 0) sred[tid >> 6] = mx;
        __syncthreads();
        mx = fmaxf(fmaxf(sred[0], sred[1]), fmaxf(sred[2], sred[3]));
        float kp = __expf(proj - mx) * inv_sqrt_m;
        ks += kp;
        #pragma unroll
        for (int d4 = 0; d4 < 16; ++d4) {
            float4 vv = ((const float4*)sV)[d4];
            kv[d4*4+0] += kp*vv.x; kv[d4*4+1] += kp*vv.y;
            kv[d4*4+2] += kp*vv.z; kv[d4*4+3] += kp*vv.w;
        }
        __syncthreads();
    }

    float* kvrow = KV + ((size_t)(b*H_ + h) * M_ + tid) * DK_;
    #pragma unroll
    for (int d = 0; d < 64; ++d) atomicAdd(&kvrow[d], kv[d]);
    atomicAdd(&ksum[(size_t)(b*H_ + h) * M_ + tid], ks);
}

// ---------------------------------------------------------------------------
// Qp = exp(Q.omega^T - rowmax)/sqrt(M); num = Qp.KV; den = Qp.ksum + EPS;
// ctx = num/den -> bf16 (B,N,H*DK). KV staged to LDS as bf16 (linear term).
// ---------------------------------------------------------------------------
__global__ __launch_bounds__(256)
void ctx_kernel(const float* __restrict__ Qf, const float* __restrict__ omega,
                const float* __restrict__ KV, const float* __restrict__ ksum,
                bf16* __restrict__ ctx)
{
    const int rblk = blockIdx.x;
    const int h = blockIdx.y, b = blockIdx.z;
    const int tid = threadIdx.x;
    const int lane = tid & 63, wave = tid >> 6;

    __shared__ bf16  sKV[M_*DK_];     // 32 KB
    __shared__ float sks[M_];
    __shared__ float sq[DK_];
    __shared__ float sqp[M_];
    __shared__ float spart[4*DK_];
    __shared__ float sredA[4], sredB[4];

    {
        const float* kvsrc = KV + (size_t)(b*H_ + h) * (M_*DK_);
        #pragma unroll
        for (int i = 0; i < 16; ++i) {
            int idx = i*256 + tid;                 // float4 index
            float4 t = ((const float4*)kvsrc)[idx];
            bf16x4 o = { (bf16)t.x, (bf16)t.y, (bf16)t.z, (bf16)t.w };
            *(bf16x4*)&sKV[idx*4] = o;
        }
        sks[tid] = ksum[(size_t)(b*H_ + h) * M_ + tid];
    }
    float om[64];
    {
        const float* op = omega + ((size_t)h * M_ + tid) * DK_;
        #pragma unroll
        for (int i = 0; i < 16; ++i)
            ((float4*)om)[i] = ((const float4*)op)[i];
    }
    const float inv_sqrt_m = rsqrtf((float)M_ + 1e-6f);
    __syncthreads();

    for (int rr = 0; rr < 64; ++rr) {
        int n = rblk*64 + rr;
        const float* qbase = Qf + (size_t)(b*N_ + n) * D_ + h*DK_;
        if (tid < 16) ((float4*)sq)[tid] = ((const float4*)qbase)[tid];
        __syncthreads();                                   // (A) q ready
        float proj = 0.f;
        #pragma unroll
        for (int d4 = 0; d4 < 16; ++d4) {
            float4 qv = ((const float4*)sq)[d4];
            proj += om[d4*4+0]*qv.x + om[d4*4+1]*qv.y + om[d4*4+2]*qv.z + om[d4*4+3]*qv.w;
        }
        float mx = proj;
        #pragma unroll
        for (int off = 32; off > 0; off >>= 1) mx = fmaxf(mx, __shfl_xor(mx, off, 64));
        if (lane == 0) sredA[wave] = mx;
        __syncthreads();                                   // (B) max ready
        mx = fmaxf(fmaxf(sredA[0], sredA[1]), fmaxf(sredA[2], sredA[3]));
        float qp = __expf(proj - mx) * inv_sqrt_m;
        sqp[tid] = qp;
        float pd = qp * sks[tid];
        #pragma unroll
        for (int off = 32; off > 0; off >>= 1) pd += __shfl_xor(pd, off, 64);
        if (lane == 0) sredB[wave] = pd;
        __syncthreads();                                   // (C) qp, den parts
        {
            float s = 0.f;
            const bf16* kvcol = sKV + wave*64*DK_ + lane;  // sKV[(wave*64+mm)][lane]
            const float* qpp = sqp + wave*64;
            #pragma unroll 8
            for (int mm = 0; mm < 64; ++mm)
                s += qpp[mm] * (float)kvcol[(size_t)mm * DK_];
            spart[wave*DK_ + lane] = s;
        }
        __syncthreads();                                   // (D) num parts
        if (tid < DK_) {
            float num = spart[tid] + spart[DK_+tid] + spart[2*DK_+tid] + spart[3*DK_+tid];
            float den = sredB[0] + sredB[1] + sredB[2] + sredB[3] + EPS_;
            ctx[(size_t)(b*N_ + n) * D_ + h*DK_ + tid] = (bf16)(num / den);
        }
        __syncthreads();                                   // (E) before sq reuse
    }
}

// ---------------------------------------------------------------------------
extern "C" void kernel_launch(void* const* d_in, const int* in_sizes, int n_in,
                              void* d_out, int out_size, void* d_ws, size_t ws_size,
                              hipStream_t stream)
{
    const float* x     = (const float*)d_in[0];
    const int*   mask  = (const int*)d_in[1];     // 1 = PAD
    const float* Wqkv  = (const float*)d_in[2];
    const float* bqkv  = (const float*)d_in[3];
    const float* Wout  = (const float*)d_in[4];
    const float* bout  = (const float*)d_in[5];
    const float* omega = (const float*)d_in[6];
    float* out = (float*)d_out;

    // Workspace: 119.6 MB total.
    //   KQ buffer: Kf during phase B, then reused as Qf.
    //   VC buffer: Vb during phase B, then reused as ctx (same 33.55 MB).
    char* w = (char*)d_ws;
    bf16*  Whi  = (bf16*)w;   w += (size_t)3*D_*D_ * 2;        // 6.29 MB
    bf16*  Wlo  = (bf16*)w;   w += (size_t)3*D_*D_ * 2;        // 6.29 MB
    bf16*  Wob  = (bf16*)w;   w += (size_t)D_*D_ * 2;          // 2.10 MB
    float* KQ   = (float*)w;  w += (size_t)R_ * D_ * 4;        // 67.11 MB
    bf16*  VC   = (bf16*)w;   w += (size_t)R_ * D_ * 2;        // 33.55 MB
    float* KV   = (float*)w;  w += (size_t)B_*H_*M_*DK_ * 4;   // 4.19 MB
    float* ksum = (float*)w;  w += (size_t)B_*H_*M_ * 4;       // 64 KB (after KV)

    // 0) weight prep: Wqkv -> hi/lo split; Wout -> plain bf16; zero KV+ksum
    int nw = 3*D_*D_;
    split_w<<<(nw + 255)/256, 256, 0, stream>>>(Wqkv, Whi, Wlo, nw);
    split_w<<<(D_*D_ + 255)/256, 256, 0, stream>>>(Wout, Wob, nullptr, D_*D_);
    int nz = B_*H_*M_*DK_ + B_*H_*M_;
    zero_f32<<<(nz + 255)/256, 256, 0, stream>>>(KV, nz);

    // 1) K,V projection (cols 1024..3071): Kf fp32 (split-GEMM accuracy), Vb bf16
    gemm_qkv<0><<<dim3(16, R_/128), 256, 0, stream>>>(x, Whi, Wlo, bqkv, KQ, VC);

    // 2) Kp features + atomic KV/ksum accumulation
    kv_accum<<<dim3(SPLIT_, H_, B_), 256, 0, stream>>>(KQ, VC, mask, omega, KV, ksum);

    // 3) Q projection (cols 0..1023) -> Qf (reuses KQ; Kf dead after kv_accum)
    gemm_qkv<1><<<dim3(8, R_/128), 256, 0, stream>>>(x, Whi, Wlo, bqkv, KQ, nullptr);

    // 4) Qp features + num/den -> ctx bf16 (reuses VC; Vb dead after kv_accum)
    ctx_kernel<<<dim3(N_/64, H_, B_), 256, 0, stream>>>(KQ, omega, KV, ksum, VC);

    // 5) output projection + bias + PAD-query zeroing -> fp32 out
    gemm_out<<<dim3(8, R_/128), 256, 0, stream>>>(VC, Wob, bout, out, mask);
}

// Round 4
// 931.260 us; speedup vs baseline: 2.2602x; 2.2602x over previous
//
#include <hip/hip_runtime.h>
#include <hip/hip_bf16.h>
#include <math.h>

#define B_  4
#define N_  4096
#define D_  1024
#define H_  16
#define DK_ 64
#define M_  256
#define R_  (B_*N_)          // 16384 rows
#define EPS_ 1e-6f
#define VTROWS_ 80           // 64 V rows + row64=ones(ksum) + 65..79 pad
#define KVROWS_ 128          // KVt bf16: 64 KV + 64=ksum_hi + 65=ksum_lo + 0-pad

typedef __bf16 bf16;
typedef __bf16 bf16x4 __attribute__((ext_vector_type(4)));
typedef __bf16 bf16x8 __attribute__((ext_vector_type(8)));
typedef float  f32x4  __attribute__((ext_vector_type(4)));

#define GLD(gp, lp) __builtin_amdgcn_global_load_lds( \
    (const __attribute__((address_space(1))) void*)(gp), \
    (__attribute__((address_space(3))) void*)(lp), 16, 0, 0)

// ---------------------------------------------------------------------------
// prep kernels
// ---------------------------------------------------------------------------
__global__ __launch_bounds__(256)
void split_w(const float* __restrict__ w, bf16* __restrict__ hi,
             bf16* __restrict__ lo, int n)
{
    int i = blockIdx.x * 256 + threadIdx.x;
    if (i < n) {
        float v = w[i];
        bf16 h = (bf16)v;
        hi[i] = h;
        if (lo) lo[i] = (bf16)(v - (float)h);
    }
}

__global__ __launch_bounds__(256)
void zero_f32(float* __restrict__ p, int n)
{
    int i = blockIdx.x * 256 + threadIdx.x;
    if (i < n) p[i] = 0.f;
}

// init VT rows 64..79: row 64 = 1.0 (ksum ones-row), rows 65..79 = 0
__global__ __launch_bounds__(256)
void init_vt(bf16* __restrict__ VT)
{
    int i = blockIdx.x * 256 + threadIdx.x;          // 64bh x 16rows x 4096
    if (i >= B_*H_*16*N_) return;
    int bh  = i >> 16;                // / (16*4096)
    int rem = i & 65535;
    int row = 64 + (rem >> 12);
    int n   = rem & (N_-1);
    VT[((size_t)bh*VTROWS_ + row)*N_ + n] = (row == 64) ? (bf16)1.0f : (bf16)0.0f;
}

// KVt32 (80 rows: 64 KV + ksum row) -> KVb bf16 (128 rows: KV, ksum_hi, ksum_lo, 0)
__global__ __launch_bounds__(256)
void pack_kv(const float* __restrict__ KVt32, bf16* __restrict__ KVb)
{
    int i = blockIdx.x * 256 + threadIdx.x;          // 64bh x 128 x 256
    if (i >= B_*H_*KVROWS_*M_) return;
    int bh  = i >> 15;                // / (128*256)
    int rem = i & 32767;
    int row = rem >> 8;
    int m   = rem & (M_-1);
    bf16 o = (bf16)0.0f;
    if (row < 64) {
        o = (bf16)KVt32[((size_t)bh*VTROWS_ + row)*M_ + m];
    } else if (row == 64) {
        o = (bf16)KVt32[((size_t)bh*VTROWS_ + 64)*M_ + m];
    } else if (row == 65) {
        float v = KVt32[((size_t)bh*VTROWS_ + 64)*M_ + m];
        o = (bf16)(v - (float)(bf16)v);
    }
    KVb[i] = o;
}

// ---------------------------------------------------------------------------
// QKV projection GEMM, fp32-accurate via 3-pass hi/lo bf16 MFMA.
// MODE 0 (KV pass, colbase=1024, grid.x=16): gcol<2048 -> Kf fp32,
//        else V -> VT transposed [b,h,d,n] bf16 (8B chunks, 4 consecutive n)
// MODE 1 (Q  pass, colbase=0,    grid.x=8):  -> Qf fp32
// ---------------------------------------------------------------------------
template<int MODE>
__global__ __launch_bounds__(256)
void gemm_qkv(const float* __restrict__ X, const bf16* __restrict__ Whi,
              const bf16* __restrict__ Wlo, const float* __restrict__ bqkv,
              float* __restrict__ QKf, bf16* __restrict__ VT)
{
    __shared__ float sX[128*64];      // 32 KB
    __shared__ bf16  sBh[128*64];     // 16 KB
    __shared__ bf16  sBl[128*64];     // 16 KB
    const int tid  = threadIdx.x;
    const int bm   = blockIdx.y * 128;
    const int bn   = blockIdx.x * 128;
    const int colbase = (MODE == 0) ? D_ : 0;
    const int lane = tid & 63, wave = tid >> 6;
    const int wm   = (wave & 1) * 64, wn = (wave >> 1) * 64;
    const int m16  = lane & 15, quad = lane >> 4;

    f32x4 acc[4][4];
    #pragma unroll
    for (int i = 0; i < 4; ++i)
        #pragma unroll
        for (int j = 0; j < 4; ++j)
            acc[i][j] = (f32x4){0.f, 0.f, 0.f, 0.f};

    for (int k0 = 0; k0 < D_; k0 += 64) {
        __syncthreads();
        #pragma unroll
        for (int it = 0; it < 8; ++it) {
            int idx = it*256 + tid;
            int row = idx >> 4, seg = idx & 15;
            GLD(X + (size_t)(bm + row) * D_ + k0 + seg*4, &sX[idx*4]);
        }
        #pragma unroll
        for (int it = 0; it < 4; ++it) {
            int idx = it*256 + tid;
            int row = idx >> 3, seg = idx & 7;
            size_t go = (size_t)(colbase + bn + row) * D_ + k0 + seg*8;
            GLD(Whi + go, &sBh[idx*8]);
            GLD(Wlo + go, &sBl[idx*8]);
        }
        __syncthreads();
        #pragma unroll
        for (int kk = 0; kk < 64; kk += 32) {
            bf16x8 ahi[4], alo[4], bhi[4], blo[4];
            #pragma unroll
            for (int i = 0; i < 4; ++i) {
                const float* p = &sX[(wm + i*16 + m16)*64 + kk + quad*8];
                float4 p0 = *(const float4*)p;
                float4 p1 = *(const float4*)(p + 4);
                float f[8] = {p0.x, p0.y, p0.z, p0.w, p1.x, p1.y, p1.z, p1.w};
                #pragma unroll
                for (int e = 0; e < 8; ++e) {
                    bf16 h = (bf16)f[e];
                    ahi[i][e] = h;
                    alo[i][e] = (bf16)(f[e] - (float)h);
                }
            }
            #pragma unroll
            for (int j = 0; j < 4; ++j) {
                bhi[j] = *(const bf16x8*)&sBh[(wn + j*16 + m16)*64 + kk + quad*8];
                blo[j] = *(const bf16x8*)&sBl[(wn + j*16 + m16)*64 + kk + quad*8];
            }
            #pragma unroll
            for (int i = 0; i < 4; ++i)
                #pragma unroll
                for (int j = 0; j < 4; ++j) {
                    acc[i][j] = __builtin_amdgcn_mfma_f32_16x16x32_bf16(
                        ahi[i], bhi[j], acc[i][j], 0, 0, 0);
                    acc[i][j] = __builtin_amdgcn_mfma_f32_16x16x32_bf16(
                        alo[i], bhi[j], acc[i][j], 0, 0, 0);
                    acc[i][j] = __builtin_amdgcn_mfma_f32_16x16x32_bf16(
                        ahi[i], blo[j], acc[i][j], 0, 0, 0);
                }
        }
    }

    #pragma unroll
    for (int j = 0; j < 4; ++j) {
        int gcol = colbase + bn + wn + j*16 + m16;
        float bv = bqkv[gcol];
        #pragma unroll
        for (int i = 0; i < 4; ++i) {
            int row0 = bm + wm + i*16 + quad*4;
            if (MODE == 0 && gcol >= 2*D_) {
                int vcol = gcol - 2*D_;
                int hh = vcol >> 6, dd = vcol & 63;
                int bb = row0 >> 12, nn = row0 & (N_-1);
                bf16x4 pk = { (bf16)(acc[i][j][0]+bv), (bf16)(acc[i][j][1]+bv),
                              (bf16)(acc[i][j][2]+bv), (bf16)(acc[i][j][3]+bv) };
                *(bf16x4*)&VT[(((size_t)bb*H_+hh)*VTROWS_ + dd)*N_ + nn] = pk;
            } else {
                #pragma unroll
                for (int r = 0; r < 4; ++r) {
                    int row = row0 + r;
                    float v = acc[i][j][r] + bv;
                    QKf[(size_t)row * D_ + gcol - colbase] = v;
                }
            }
        }
    }
}

// ---------------------------------------------------------------------------
// feat: proj = QK . omega^T per (b,h) via single-K-step 3-pass hi/lo MFMA,
// rowmax intra-wave (wave owns 32 full rows), Phi = exp(proj-mx)/sqrt(M).
// TRANS=1 (K side): zero PAD rows, store PhiT [b,h,m,n] (bf16x4, 4 consec n).
// TRANS=0 (Q side): store Phi  [b,h,n,m] (scalar bf16, 32B/quad segments).
// ---------------------------------------------------------------------------
template<int TRANS>
__global__ __launch_bounds__(256)
void feat_kernel(const float* __restrict__ QK, const bf16* __restrict__ omhi,
                 const bf16* __restrict__ omlo, const int* __restrict__ mask,
                 bf16* __restrict__ Phi)
{
    __shared__ float sA[128*64];      // 32 KB
    __shared__ int   sMask[128];
    const int nblk = blockIdx.x, h = blockIdx.y, b = blockIdx.z;
    const int tid = threadIdx.x, lane = tid & 63, wave = tid >> 6;
    const int m16 = lane & 15, quad = lane >> 4;
    const float inv_sqrt_m = rsqrtf((float)M_ + 1e-6f);

    // stage 128 rows x 64 fp32 (head-slice of Q/K)
    #pragma unroll
    for (int it = 0; it < 8; ++it) {
        int idx = it*256 + tid;
        int row = idx >> 4, seg = idx & 15;
        GLD(QK + (size_t)(b*N_ + nblk*128 + row) * D_ + h*DK_ + seg*4, &sA[idx*4]);
    }
    if (TRANS && tid < 128) sMask[tid] = mask[b*N_ + nblk*128 + tid];
    __syncthreads();

    // A fragments, hi/lo split in-register. wave rows: wave*32 .. +32
    bf16x8 ah[2][2], al[2][2];        // [rowtile][kstep]
    #pragma unroll
    for (int i = 0; i < 2; ++i)
        #pragma unroll
        for (int k = 0; k < 2; ++k) {
            const float* p = &sA[(wave*32 + i*16 + m16)*64 + k*32 + quad*8];
            float4 p0 = *(const float4*)p;
            float4 p1 = *(const float4*)(p + 4);
            float f[8] = {p0.x, p0.y, p0.z, p0.w, p1.x, p1.y, p1.z, p1.w};
            #pragma unroll
            for (int e = 0; e < 8; ++e) {
                bf16 hh = (bf16)f[e];
                ah[i][k][e] = hh;
                al[i][k][e] = (bf16)(f[e] - (float)hh);
            }
        }

    f32x4 acc[2][16];
    #pragma unroll
    for (int i = 0; i < 2; ++i)
        #pragma unroll
        for (int j = 0; j < 16; ++j)
            acc[i][j] = (f32x4){0.f, 0.f, 0.f, 0.f};

    const bf16* omh = omhi + (size_t)h * M_ * DK_;
    const bf16* oml = omlo + (size_t)h * M_ * DK_;
    #pragma unroll
    for (int j = 0; j < 16; ++j) {
        size_t ro = (size_t)(j*16 + m16) * DK_ + quad*8;
        bf16x8 bh0 = *(const bf16x8*)&omh[ro];
        bf16x8 bh1 = *(const bf16x8*)&omh[ro + 32];
        bf16x8 bl0 = *(const bf16x8*)&oml[ro];
        bf16x8 bl1 = *(const bf16x8*)&oml[ro + 32];
        #pragma unroll
        for (int i = 0; i < 2; ++i) {
            acc[i][j] = __builtin_amdgcn_mfma_f32_16x16x32_bf16(ah[i][0], bh0, acc[i][j], 0,0,0);
            acc[i][j] = __builtin_amdgcn_mfma_f32_16x16x32_bf16(al[i][0], bh0, acc[i][j], 0,0,0);
            acc[i][j] = __builtin_amdgcn_mfma_f32_16x16x32_bf16(ah[i][0], bl0, acc[i][j], 0,0,0);
            acc[i][j] = __builtin_amdgcn_mfma_f32_16x16x32_bf16(ah[i][1], bh1, acc[i][j], 0,0,0);
            acc[i][j] = __builtin_amdgcn_mfma_f32_16x16x32_bf16(al[i][1], bh1, acc[i][j], 0,0,0);
            acc[i][j] = __builtin_amdgcn_mfma_f32_16x16x32_bf16(ah[i][1], bl1, acc[i][j], 0,0,0);
        }
    }

    // rowmax over 256 features (16 tiles in-lane + shuffle over m16 bits), exp
    #pragma unroll
    for (int i = 0; i < 2; ++i)
        #pragma unroll
        for (int r = 0; r < 4; ++r) {
            float mx = acc[i][0][r];
            #pragma unroll
            for (int j = 1; j < 16; ++j) mx = fmaxf(mx, acc[i][j][r]);
            mx = fmaxf(mx, __shfl_xor(mx, 1, 64));
            mx = fmaxf(mx, __shfl_xor(mx, 2, 64));
            mx = fmaxf(mx, __shfl_xor(mx, 4, 64));
            mx = fmaxf(mx, __shfl_xor(mx, 8, 64));
            #pragma unroll
            for (int j = 0; j < 16; ++j)
                acc[i][j][r] = __expf(acc[i][j][r] - mx) * inv_sqrt_m;
        }

    const int bh = b*H_ + h;
    if (TRANS) {
        #pragma unroll
        for (int i = 0; i < 2; ++i) {
            int lrow0 = wave*32 + i*16 + quad*4;
            int n0 = nblk*128 + lrow0;
            #pragma unroll
            for (int j = 0; j < 16; ++j) {
                bf16x4 pk;
                #pragma unroll
                for (int r = 0; r < 4; ++r)
                    pk[r] = sMask[lrow0 + r] ? (bf16)0.0f : (bf16)acc[i][j][r];
                *(bf16x4*)&Phi[((size_t)bh*M_ + j*16 + m16)*N_ + n0] = pk;
            }
        }
    } else {
        #pragma unroll
        for (int i = 0; i < 2; ++i) {
            int n0 = nblk*128 + wave*32 + i*16 + quad*4;
            #pragma unroll
            for (int j = 0; j < 16; ++j)
                #pragma unroll
                for (int r = 0; r < 4; ++r)
                    Phi[((size_t)bh*N_ + n0 + r)*M_ + j*16 + m16] = (bf16)acc[i][j][r];
        }
    }
}

// ---------------------------------------------------------------------------
// KVt32[d][m] += sum_n VT[d][n] * PhiT[m][n]   per (b,h); n split 4-way,
// fp32 atomics. Output 80 x 256 (row 64 = ksum via VT ones-row).
// ---------------------------------------------------------------------------
__global__ __launch_bounds__(256)
void kv_gemm(const bf16* __restrict__ PhiT, const bf16* __restrict__ VT,
             float* __restrict__ KVt32)
{
    __shared__ bf16 sP[256*64];       // 32 KB
    __shared__ bf16 sV[VTROWS_*64];   // 10 KB
    const int nsp = blockIdx.x;       // 0..3
    const int bh  = blockIdx.z * H_ + blockIdx.y;
    const int tid = threadIdx.x, lane = tid & 63, wave = tid >> 6;
    const int m16 = lane & 15, quad = lane >> 4;
    const int wm  = wave * 64;        // wave's m-range

    f32x4 acc[5][4];                  // [dtile][jtile]
    #pragma unroll
    for (int d = 0; d < 5; ++d)
        #pragma unroll
        for (int j = 0; j < 4; ++j)
            acc[d][j] = (f32x4){0.f, 0.f, 0.f, 0.f};

    for (int n0 = nsp*1024; n0 < nsp*1024 + 1024; n0 += 64) {
        __syncthreads();
        #pragma unroll
        for (int it = 0; it < 8; ++it) {
            int idx = it*256 + tid;
            int row = idx >> 3, seg = idx & 7;
            GLD(PhiT + ((size_t)bh*M_ + row)*N_ + n0 + seg*8, &sP[idx*8]);
        }
        #pragma unroll
        for (int it = 0; it < 3; ++it) {
            int idx = it*256 + tid;
            if (idx < VTROWS_*8) {
                int row = idx >> 3, seg = idx & 7;
                GLD(VT + ((size_t)bh*VTROWS_ + row)*N_ + n0 + seg*8, &sV[idx*8]);
            }
        }
        __syncthreads();
        #pragma unroll
        for (int kk = 0; kk < 64; kk += 32) {
            bf16x8 av[5], bp[4];
            #pragma unroll
            for (int d = 0; d < 5; ++d)
                av[d] = *(const bf16x8*)&sV[(d*16 + m16)*64 + kk + quad*8];
            #pragma unroll
            for (int j = 0; j < 4; ++j)
                bp[j] = *(const bf16x8*)&sP[(wm + j*16 + m16)*64 + kk + quad*8];
            #pragma unroll
            for (int d = 0; d < 5; ++d)
                #pragma unroll
                for (int j = 0; j < 4; ++j)
                    acc[d][j] = __builtin_amdgcn_mfma_f32_16x16x32_bf16(
                        av[d], bp[j], acc[d][j], 0, 0, 0);
        }
    }

    #pragma unroll
    for (int d = 0; d < 5; ++d)
        #pragma unroll
        for (int j = 0; j < 4; ++j) {
            int drow = d*16 + quad*4;
            int m = wm + j*16 + m16;
            #pragma unroll
            for (int r = 0; r < 4; ++r)
                atomicAdd(&KVt32[((size_t)bh*VTROWS_ + drow + r)*M_ + m],
                          acc[d][j][r]);
        }
}

// ---------------------------------------------------------------------------
// ctx = (PhiQ @ KVb^T)/den per (b,h): num cols 0..63, den = col64+col65+EPS.
// A = PhiQ [n][m], W = KVb [128][256] (K=256, 4 k-steps). Out: ctx bf16 [n][D].
// ---------------------------------------------------------------------------
__global__ __launch_bounds__(256)
void ctx_gemm(const bf16* __restrict__ PhiQ, const bf16* __restrict__ KVb,
              bf16* __restrict__ ctx)
{
    __shared__ bf16 sA[128*64];
    __shared__ bf16 sW[128*64];
    __shared__ float sden[2][128];
    const int nblk = blockIdx.x, h = blockIdx.y, b = blockIdx.z;
    const int bh = b*H_ + h;
    const int tid = threadIdx.x, lane = tid & 63, wave = tid >> 6;
    const int wm = (wave & 1) * 64, wn = (wave >> 1) * 64;
    const int m16 = lane & 15, quad = lane >> 4;

    f32x4 acc[4][4];
    #pragma unroll
    for (int i = 0; i < 4; ++i)
        #pragma unroll
        for (int j = 0; j < 4; ++j)
            acc[i][j] = (f32x4){0.f, 0.f, 0.f, 0.f};

    for (int k0 = 0; k0 < M_; k0 += 64) {
        __syncthreads();
        #pragma unroll
        for (int it = 0; it < 4; ++it) {
            int idx = it*256 + tid;
            int row = idx >> 3, seg = idx & 7;
            GLD(PhiQ + ((size_t)bh*N_ + nblk*128 + row)*M_ + k0 + seg*8, &sA[idx*8]);
            GLD(KVb  + ((size_t)bh*KVROWS_ + row)*M_ + k0 + seg*8, &sW[idx*8]);
        }
        __syncthreads();
        #pragma unroll
        for (int kk = 0; kk < 64; kk += 32) {
            bf16x8 af[4], wf[4];
            #pragma unroll
            for (int i = 0; i < 4; ++i)
                af[i] = *(const bf16x8*)&sA[(wm + i*16 + m16)*64 + kk + quad*8];
            #pragma unroll
            for (int j = 0; j < 4; ++j)
                wf[j] = *(const bf16x8*)&sW[(wn + j*16 + m16)*64 + kk + quad*8];
            #pragma unroll
            for (int i = 0; i < 4; ++i)
                #pragma unroll
                for (int j = 0; j < 4; ++j)
                    acc[i][j] = __builtin_amdgcn_mfma_f32_16x16x32_bf16(
                        af[i], wf[j], acc[i][j], 0, 0, 0);
        }
    }

    // den: cols 64(hi),65(lo) live in waves wn==64, jtile 0, m16 in {0,1}
    if (wn == 64 && m16 < 2) {
        #pragma unroll
        for (int i = 0; i < 4; ++i)
            #pragma unroll
            for (int r = 0; r < 4; ++r)
                sden[m16][wm + i*16 + quad*4 + r] = acc[i][0][r];
    }
    __syncthreads();
    if (wn == 0) {
        #pragma unroll
        for (int i = 0; i < 4; ++i) {
            int lrow0 = wm + i*16 + quad*4;
            #pragma unroll
            for (int r = 0; r < 4; ++r) {
                int lrow = lrow0 + r;
                int n = nblk*128 + lrow;
                float den = sden[0][lrow] + sden[1][lrow] + EPS_;
                #pragma unroll
                for (int j = 0; j < 4; ++j)
                    ctx[(size_t)(b*N_ + n)*D_ + h*DK_ + j*16 + m16] =
                        (bf16)(acc[i][j][r] / den);
            }
        }
    }
}

// ---------------------------------------------------------------------------
// Output projection: out = mask ? 0 : ctx @ Wout^T + bout   (bf16 MFMA, fp32 out)
// ---------------------------------------------------------------------------
__global__ __launch_bounds__(256)
void gemm_out(const bf16* __restrict__ A, const bf16* __restrict__ W,
              const float* __restrict__ bias, float* __restrict__ C,
              const int* __restrict__ mask)
{
    __shared__ bf16 sA[128*64];
    __shared__ bf16 sB[128*64];
    const int tid  = threadIdx.x;
    const int bm   = blockIdx.y * 128;
    const int bn   = blockIdx.x * 128;
    const int lane = tid & 63, wave = tid >> 6;
    const int wm   = (wave & 1) * 64, wn = (wave >> 1) * 64;
    const int m16  = lane & 15, quad = lane >> 4;

    f32x4 acc[4][4];
    #pragma unroll
    for (int i = 0; i < 4; ++i)
        #pragma unroll
        for (int j = 0; j < 4; ++j)
            acc[i][j] = (f32x4){0.f, 0.f, 0.f, 0.f};

    for (int k0 = 0; k0 < D_; k0 += 64) {
        __syncthreads();
        #pragma unroll
        for (int it = 0; it < 4; ++it) {
            int idx = it*256 + tid;
            int row = idx >> 3, seg = idx & 7;
            GLD(A + (size_t)(bm + row) * D_ + k0 + seg*8, &sA[idx*8]);
            GLD(W + (size_t)(bn + row) * D_ + k0 + seg*8, &sB[idx*8]);
        }
        __syncthreads();
        #pragma unroll
        for (int kk = 0; kk < 64; kk += 32) {
            bf16x8 af[4], bfr[4];
            #pragma unroll
            for (int i = 0; i < 4; ++i)
                af[i] = *(const bf16x8*)&sA[(wm + i*16 + m16)*64 + kk + quad*8];
            #pragma unroll
            for (int j = 0; j < 4; ++j)
                bfr[j] = *(const bf16x8*)&sB[(wn + j*16 + m16)*64 + kk + quad*8];
            #pragma unroll
            for (int i = 0; i < 4; ++i)
                #pragma unroll
                for (int j = 0; j < 4; ++j)
                    acc[i][j] = __builtin_amdgcn_mfma_f32_16x16x32_bf16(
                        af[i], bfr[j], acc[i][j], 0, 0, 0);
        }
    }

    #pragma unroll
    for (int j = 0; j < 4; ++j) {
        int col = bn + wn + j*16 + m16;
        float bv = bias[col];
        #pragma unroll
        for (int i = 0; i < 4; ++i) {
            int row0 = bm + wm + i*16 + quad*4;
            #pragma unroll
            for (int r = 0; r < 4; ++r) {
                int row = row0 + r;
                float v = acc[i][j][r] + bv;
                if (mask[row] != 0) v = 0.0f;
                C[(size_t)row * D_ + col] = v;
            }
        }
    }
}

// ---------------------------------------------------------------------------
extern "C" void kernel_launch(void* const* d_in, const int* in_sizes, int n_in,
                              void* d_out, int out_size, void* d_ws, size_t ws_size,
                              hipStream_t stream)
{
    const float* x     = (const float*)d_in[0];
    const int*   mask  = (const int*)d_in[1];     // 1 = PAD
    const float* Wqkv  = (const float*)d_in[2];
    const float* bqkv  = (const float*)d_in[3];
    const float* Wout  = (const float*)d_in[4];
    const float* bout  = (const float*)d_in[5];
    const float* omega = (const float*)d_in[6];
    float* out = (float*)d_out;

    // Workspace: 167.8 MB (<= 172 MB proven-safe).
    char* w = (char*)d_ws;
    bf16*  Whi   = (bf16*)w;   w += (size_t)3*D_*D_ * 2;              // 6.29 MB
    bf16*  Wlo   = (bf16*)w;   w += (size_t)3*D_*D_ * 2;              // 6.29 MB
    bf16*  Wob   = (bf16*)w;   w += (size_t)D_*D_ * 2;                // 2.10 MB
    bf16*  omhi  = (bf16*)w;   w += (size_t)H_*M_*DK_ * 2;            // 0.52 MB
    bf16*  omlo  = (bf16*)w;   w += (size_t)H_*M_*DK_ * 2;            // 0.52 MB
    float* KQ    = (float*)w;  w += (size_t)R_ * D_ * 4;              // 67.11 MB (Kf->Qf->ctx)
    bf16*  VT    = (bf16*)w;   w += (size_t)B_*H_*VTROWS_*N_ * 2;     // 41.94 MB
    bf16*  PH    = (bf16*)w;   w += (size_t)B_*H_*N_*M_ * 2;          // 33.55 MB (PhiT->PhiQ)
    float* KVt32 = (float*)w;  w += (size_t)B_*H_*VTROWS_*M_ * 4;     // 5.24 MB
    bf16*  KVb   = (bf16*)w;   w += (size_t)B_*H_*KVROWS_*M_ * 2;     // 4.19 MB
    bf16*  VC    = (bf16*)KQ;                                         // ctx aliases KQ

    // 0) prep
    split_w<<<(3*D_*D_ + 255)/256, 256, 0, stream>>>(Wqkv, Whi, Wlo, 3*D_*D_);
    split_w<<<(D_*D_ + 255)/256, 256, 0, stream>>>(Wout, Wob, nullptr, D_*D_);
    split_w<<<(H_*M_*DK_ + 255)/256, 256, 0, stream>>>(omega, omhi, omlo, H_*M_*DK_);
    zero_f32<<<(B_*H_*VTROWS_*M_ + 255)/256, 256, 0, stream>>>(KVt32, B_*H_*VTROWS_*M_);
    init_vt<<<(B_*H_*16*N_ + 255)/256, 256, 0, stream>>>(VT);

    // 1) K,V projection: Kf fp32 -> KQ, V -> VT (transposed, +ones row via init)
    gemm_qkv<0><<<dim3(16, R_/128), 256, 0, stream>>>(x, Whi, Wlo, bqkv, KQ, VT);

    // 2) K features -> PhiT (masked)
    feat_kernel<1><<<dim3(N_/128, H_, B_), 256, 0, stream>>>(KQ, omhi, omlo, mask, PH);

    // 3) Q projection -> Qf (overwrites Kf; Kf dead after feat-K)
    gemm_qkv<1><<<dim3(8, R_/128), 256, 0, stream>>>(x, Whi, Wlo, bqkv, KQ, nullptr);

    // 4) KV + ksum: PhiT x VT -> KVt32 (atomics)
    kv_gemm<<<dim3(4, H_, B_), 256, 0, stream>>>(PH, VT, KVt32);

    // 5) pack KVt32 -> KVb bf16 (ksum hi/lo rows 64/65, zero pad to 128)
    pack_kv<<<(B_*H_*KVROWS_*M_ + 255)/256, 256, 0, stream>>>(KVt32, KVb);

    // 6) Q features -> PhiQ (reuses PH; PhiT dead after kv_gemm)
    feat_kernel<0><<<dim3(N_/128, H_, B_), 256, 0, stream>>>(KQ, omhi, omlo, mask, PH);

    // 7) ctx = num/den -> VC bf16 (reuses KQ; Qf dead after feat-Q)
    ctx_gemm<<<dim3(N_/128, H_, B_), 256, 0, stream>>>(PH, KVb, VC);

    // 8) output projection + bias + PAD-query zeroing -> fp32 out
    gemm_out<<<dim3(8, R_/128), 256, 0, stream>>>(VC, Wob, bout, out, mask);
}

// Round 6
// 663.224 us; speedup vs baseline: 3.1736x; 1.4041x over previous
//
#include <hip/hip_runtime.h>
#include <hip/hip_bf16.h>
#include <math.h>

#define B_  4
#define N_  4096
#define D_  1024
#define H_  16
#define DK_ 64
#define M_  256
#define R_  (B_*N_)          // 16384 rows
#define EPS_ 1e-6f
#define VTROWS_ 80           // 64 V rows + row64=ones(ksum) + 65..79 pad
#define KVROWS_ 128          // KVb bf16: 64 KV + 64=ksum_hi + 65=ksum_lo + 0-pad

typedef __bf16 bf16;
typedef __bf16 bf16x4 __attribute__((ext_vector_type(4)));
typedef __bf16 bf16x8 __attribute__((ext_vector_type(8)));
typedef _Float16 f16;
typedef _Float16 f16x8 __attribute__((ext_vector_type(8)));
typedef float  f32x4  __attribute__((ext_vector_type(4)));

#define GLD(gp, lp) __builtin_amdgcn_global_load_lds( \
    (const __attribute__((address_space(1))) void*)(gp), \
    (__attribute__((address_space(3))) void*)(lp), 16, 0, 0)

// ---------------------------------------------------------------------------
// prep kernels
// ---------------------------------------------------------------------------
// fp32 -> f16 hi (+ optional f16 lo residual)
__global__ __launch_bounds__(256)
void split_f16(const float* __restrict__ in, f16* __restrict__ hi,
               f16* __restrict__ lo, int n)
{
    int i = blockIdx.x * 256 + threadIdx.x;
    if (i < n) {
        float v = in[i];
        f16 h = (f16)v;
        hi[i] = h;
        if (lo) lo[i] = (f16)(v - (float)h);
    }
}

__global__ __launch_bounds__(256)
void f32_to_bf16(const float* __restrict__ in, bf16* __restrict__ o, int n)
{
    int i = blockIdx.x * 256 + threadIdx.x;
    if (i < n) o[i] = (bf16)in[i];
}

__global__ __launch_bounds__(256)
void zero_f32(float* __restrict__ p, int n)
{
    int i = blockIdx.x * 256 + threadIdx.x;
    if (i < n) p[i] = 0.f;
}

// init VT rows 64..79: row 64 = 1.0 (ksum ones-row), rows 65..79 = 0
__global__ __launch_bounds__(256)
void init_vt(bf16* __restrict__ VT)
{
    int i = blockIdx.x * 256 + threadIdx.x;          // 64bh x 16rows x 4096
    if (i >= B_*H_*16*N_) return;
    int bh  = i >> 16;
    int rem = i & 65535;
    int row = 64 + (rem >> 12);
    int n   = rem & (N_-1);
    VT[((size_t)bh*VTROWS_ + row)*N_ + n] = (row == 64) ? (bf16)1.0f : (bf16)0.0f;
}

// KVt32 (80 rows: 64 KV + ksum row) -> KVb bf16 (128 rows: KV, ksum_hi, ksum_lo, 0)
__global__ __launch_bounds__(256)
void pack_kv(const float* __restrict__ KVt32, bf16* __restrict__ KVb)
{
    int i = blockIdx.x * 256 + threadIdx.x;          // 64bh x 128 x 256
    if (i >= B_*H_*KVROWS_*M_) return;
    int bh  = i >> 15;
    int rem = i & 32767;
    int row = rem >> 8;
    int m   = rem & (M_-1);
    bf16 o = (bf16)0.0f;
    if (row < 64) {
        o = (bf16)KVt32[((size_t)bh*VTROWS_ + row)*M_ + m];
    } else if (row == 64) {
        o = (bf16)KVt32[((size_t)bh*VTROWS_ + 64)*M_ + m];
    } else if (row == 65) {
        float v = KVt32[((size_t)bh*VTROWS_ + 64)*M_ + m];
        o = (bf16)(v - (float)(bf16)v);
    }
    KVb[i] = o;
}

// ---------------------------------------------------------------------------
// Unified QKV projection, single-pass fp16 MFMA.
// col<1024 -> Qh fp16; col<2048 -> Kh fp16; else V -> VT bf16 transposed
// [b,h,d,n] (+bias). 128x128 tile, BK=64, 32 KB LDS.
// ---------------------------------------------------------------------------
__global__ __launch_bounds__(256)
void gemm_qkv(const f16* __restrict__ X, const f16* __restrict__ Wh,
              const float* __restrict__ bqkv,
              f16* __restrict__ Qh, f16* __restrict__ Kh, bf16* __restrict__ VT)
{
    __shared__ f16 sA[128*64];        // 16 KB
    __shared__ f16 sB[128*64];        // 16 KB
    const int tid  = threadIdx.x;
    const int bm   = blockIdx.y * 128;
    const int bn   = blockIdx.x * 128;
    const int lane = tid & 63, wave = tid >> 6;
    const int wm   = (wave & 1) * 64, wn = (wave >> 1) * 64;
    const int m16  = lane & 15, quad = lane >> 4;

    f32x4 acc[4][4];
    #pragma unroll
    for (int i = 0; i < 4; ++i)
        #pragma unroll
        for (int j = 0; j < 4; ++j)
            acc[i][j] = (f32x4){0.f, 0.f, 0.f, 0.f};

    for (int k0 = 0; k0 < D_; k0 += 64) {
        __syncthreads();
        #pragma unroll
        for (int it = 0; it < 4; ++it) {
            int idx = it*256 + tid;
            int row = idx >> 3, seg = idx & 7;
            GLD(X  + (size_t)(bm + row) * D_ + k0 + seg*8, &sA[idx*8]);
            GLD(Wh + (size_t)(bn + row) * D_ + k0 + seg*8, &sB[idx*8]);
        }
        __syncthreads();
        #pragma unroll
        for (int kk = 0; kk < 64; kk += 32) {
            f16x8 af[4], bfr[4];
            #pragma unroll
            for (int i = 0; i < 4; ++i)
                af[i] = *(const f16x8*)&sA[(wm + i*16 + m16)*64 + kk + quad*8];
            #pragma unroll
            for (int j = 0; j < 4; ++j)
                bfr[j] = *(const f16x8*)&sB[(wn + j*16 + m16)*64 + kk + quad*8];
            #pragma unroll
            for (int i = 0; i < 4; ++i)
                #pragma unroll
                for (int j = 0; j < 4; ++j)
                    acc[i][j] = __builtin_amdgcn_mfma_f32_16x16x32_f16(
                        af[i], bfr[j], acc[i][j], 0, 0, 0);
        }
    }

    #pragma unroll
    for (int j = 0; j < 4; ++j) {
        int gcol = bn + wn + j*16 + m16;
        float bv = bqkv[gcol];
        #pragma unroll
        for (int i = 0; i < 4; ++i) {
            int row0 = bm + wm + i*16 + quad*4;
            if (gcol >= 2*D_) {
                int vcol = gcol - 2*D_;
                int hh = vcol >> 6, dd = vcol & 63;
                int bb = row0 >> 12, nn = row0 & (N_-1);
                bf16x4 pk = { (bf16)(acc[i][j][0]+bv), (bf16)(acc[i][j][1]+bv),
                              (bf16)(acc[i][j][2]+bv), (bf16)(acc[i][j][3]+bv) };
                *(bf16x4*)&VT[(((size_t)bb*H_+hh)*VTROWS_ + dd)*N_ + nn] = pk;
            } else if (gcol >= D_) {
                #pragma unroll
                for (int r = 0; r < 4; ++r)
                    Kh[(size_t)(row0+r) * D_ + gcol - D_] = (f16)(acc[i][j][r] + bv);
            } else {
                #pragma unroll
                for (int r = 0; r < 4; ++r)
                    Qh[(size_t)(row0+r) * D_ + gcol] = (f16)(acc[i][j][r] + bv);
            }
        }
    }
}

// ---------------------------------------------------------------------------
// feat: proj = QK . omega^T per (b,h), fp16 MFMA with omega hi/lo 2-pass
// (kills omega-rounding noise), rowmax intra-wave, Phi = exp(proj-mx)/sqrt(M).
// TRANS=1 (K side): zero PAD rows, store PhiT [b,h,m,n] (bf16x4).
// TRANS=0 (Q side): store Phi  [b,h,n,m].
// ---------------------------------------------------------------------------
template<int TRANS>
__global__ __launch_bounds__(256)
void feat_kernel(const f16* __restrict__ QK, const f16* __restrict__ omhi,
                 const f16* __restrict__ omlo, const int* __restrict__ mask,
                 bf16* __restrict__ Phi)
{
    __shared__ f16 sA[128*64];        // 16 KB
    __shared__ int sMask[128];
    const int nblk = blockIdx.x, h = blockIdx.y, b = blockIdx.z;
    const int tid = threadIdx.x, lane = tid & 63, wave = tid >> 6;
    const int m16 = lane & 15, quad = lane >> 4;
    const float inv_sqrt_m = rsqrtf((float)M_ + 1e-6f);

    #pragma unroll
    for (int it = 0; it < 4; ++it) {
        int idx = it*256 + tid;
        int row = idx >> 3, seg = idx & 7;
        GLD(QK + (size_t)(b*N_ + nblk*128 + row) * D_ + h*DK_ + seg*8, &sA[idx*8]);
    }
    if (TRANS && tid < 128) sMask[tid] = mask[b*N_ + nblk*128 + tid];
    __syncthreads();

    f16x8 ah[2][2];                   // [rowtile][kstep]
    #pragma unroll
    for (int i = 0; i < 2; ++i)
        #pragma unroll
        for (int k = 0; k < 2; ++k)
            ah[i][k] = *(const f16x8*)&sA[(wave*32 + i*16 + m16)*64 + k*32 + quad*8];

    f32x4 acc[2][16];
    #pragma unroll
    for (int i = 0; i < 2; ++i)
        #pragma unroll
        for (int j = 0; j < 16; ++j)
            acc[i][j] = (f32x4){0.f, 0.f, 0.f, 0.f};

    const f16* omh = omhi + (size_t)h * M_ * DK_;
    const f16* oml = omlo + (size_t)h * M_ * DK_;
    #pragma unroll
    for (int j = 0; j < 16; ++j) {
        size_t ro = (size_t)(j*16 + m16) * DK_ + quad*8;
        f16x8 bh0 = *(const f16x8*)&omh[ro];
        f16x8 bh1 = *(const f16x8*)&omh[ro + 32];
        f16x8 bl0 = *(const f16x8*)&oml[ro];
        f16x8 bl1 = *(const f16x8*)&oml[ro + 32];
        #pragma unroll
        for (int i = 0; i < 2; ++i) {
            acc[i][j] = __builtin_amdgcn_mfma_f32_16x16x32_f16(ah[i][0], bh0, acc[i][j], 0,0,0);
            acc[i][j] = __builtin_amdgcn_mfma_f32_16x16x32_f16(ah[i][0], bl0, acc[i][j], 0,0,0);
            acc[i][j] = __builtin_amdgcn_mfma_f32_16x16x32_f16(ah[i][1], bh1, acc[i][j], 0,0,0);
            acc[i][j] = __builtin_amdgcn_mfma_f32_16x16x32_f16(ah[i][1], bl1, acc[i][j], 0,0,0);
        }
    }

    // rowmax over 256 features (16 tiles in-lane + shuffle over m16 bits), exp
    #pragma unroll
    for (int i = 0; i < 2; ++i)
        #pragma unroll
        for (int r = 0; r < 4; ++r) {
            float mx = acc[i][0][r];
            #pragma unroll
            for (int j = 1; j < 16; ++j) mx = fmaxf(mx, acc[i][j][r]);
            mx = fmaxf(mx, __shfl_xor(mx, 1, 64));
            mx = fmaxf(mx, __shfl_xor(mx, 2, 64));
            mx = fmaxf(mx, __shfl_xor(mx, 4, 64));
            mx = fmaxf(mx, __shfl_xor(mx, 8, 64));
            #pragma unroll
            for (int j = 0; j < 16; ++j)
                acc[i][j][r] = __expf(acc[i][j][r] - mx) * inv_sqrt_m;
        }

    const int bh = b*H_ + h;
    if (TRANS) {
        #pragma unroll
        for (int i = 0; i < 2; ++i) {
            int lrow0 = wave*32 + i*16 + quad*4;
            int n0 = nblk*128 + lrow0;
            #pragma unroll
            for (int j = 0; j < 16; ++j) {
                bf16x4 pk;
                #pragma unroll
                for (int r = 0; r < 4; ++r)
                    pk[r] = sMask[lrow0 + r] ? (bf16)0.0f : (bf16)acc[i][j][r];
                *(bf16x4*)&Phi[((size_t)bh*M_ + j*16 + m16)*N_ + n0] = pk;
            }
        }
    } else {
        #pragma unroll
        for (int i = 0; i < 2; ++i) {
            int n0 = nblk*128 + wave*32 + i*16 + quad*4;
            #pragma unroll
            for (int j = 0; j < 16; ++j)
                #pragma unroll
                for (int r = 0; r < 4; ++r)
                    Phi[((size_t)bh*N_ + n0 + r)*M_ + j*16 + m16] = (bf16)acc[i][j][r];
        }
    }
}

// ---------------------------------------------------------------------------
// KVt32[d][m] += sum_n VT[d][n] * PhiT[m][n]   per (b,h); n split 4-way,
// fp32 atomics. Output 80 x 256 (row 64 = ksum via VT ones-row).
// ---------------------------------------------------------------------------
__global__ __launch_bounds__(256)
void kv_gemm(const bf16* __restrict__ PhiT, const bf16* __restrict__ VT,
             float* __restrict__ KVt32)
{
    __shared__ bf16 sP[256*64];       // 32 KB
    __shared__ bf16 sV[VTROWS_*64];   // 10 KB
    const int nsp = blockIdx.x;       // 0..3
    const int bh  = blockIdx.z * H_ + blockIdx.y;
    const int tid = threadIdx.x, lane = tid & 63, wave = tid >> 6;
    const int m16 = lane & 15, quad = lane >> 4;
    const int wm  = wave * 64;

    f32x4 acc[5][4];
    #pragma unroll
    for (int d = 0; d < 5; ++d)
        #pragma unroll
        for (int j = 0; j < 4; ++j)
            acc[d][j] = (f32x4){0.f, 0.f, 0.f, 0.f};

    for (int n0 = nsp*1024; n0 < nsp*1024 + 1024; n0 += 64) {
        __syncthreads();
        #pragma unroll
        for (int it = 0; it < 8; ++it) {
            int idx = it*256 + tid;
            int row = idx >> 3, seg = idx & 7;
            GLD(PhiT + ((size_t)bh*M_ + row)*N_ + n0 + seg*8, &sP[idx*8]);
        }
        #pragma unroll
        for (int it = 0; it < 3; ++it) {
            int idx = it*256 + tid;
            if (idx < VTROWS_*8) {
                int row = idx >> 3, seg = idx & 7;
                GLD(VT + ((size_t)bh*VTROWS_ + row)*N_ + n0 + seg*8, &sV[idx*8]);
            }
        }
        __syncthreads();
        #pragma unroll
        for (int kk = 0; kk < 64; kk += 32) {
            bf16x8 av[5], bp[4];
            #pragma unroll
            for (int d = 0; d < 5; ++d)
                av[d] = *(const bf16x8*)&sV[(d*16 + m16)*64 + kk + quad*8];
            #pragma unroll
            for (int j = 0; j < 4; ++j)
                bp[j] = *(const bf16x8*)&sP[(wm + j*16 + m16)*64 + kk + quad*8];
            #pragma unroll
            for (int d = 0; d < 5; ++d)
                #pragma unroll
                for (int j = 0; j < 4; ++j)
                    acc[d][j] = __builtin_amdgcn_mfma_f32_16x16x32_bf16(
                        av[d], bp[j], acc[d][j], 0, 0, 0);
        }
    }

    #pragma unroll
    for (int d = 0; d < 5; ++d)
        #pragma unroll
        for (int j = 0; j < 4; ++j) {
            int drow = d*16 + quad*4;
            int m = wm + j*16 + m16;
            #pragma unroll
            for (int r = 0; r < 4; ++r)
                atomicAdd(&KVt32[((size_t)bh*VTROWS_ + drow + r)*M_ + m],
                          acc[d][j][r]);
        }
}

// ---------------------------------------------------------------------------
// ctx = (PhiQ @ KVb^T)/den per (b,h): num cols 0..63, den = col64+col65+EPS.
// ---------------------------------------------------------------------------
__global__ __launch_bounds__(256)
void ctx_gemm(const bf16* __restrict__ PhiQ, const bf16* __restrict__ KVb,
              bf16* __restrict__ ctx)
{
    __shared__ bf16 sA[128*64];
    __shared__ bf16 sW[128*64];
    __shared__ float sden[2][128];
    const int nblk = blockIdx.x, h = blockIdx.y, b = blockIdx.z;
    const int bh = b*H_ + h;
    const int tid = threadIdx.x, lane = tid & 63, wave = tid >> 6;
    const int wm = (wave & 1) * 64, wn = (wave >> 1) * 64;
    const int m16 = lane & 15, quad = lane >> 4;

    f32x4 acc[4][4];
    #pragma unroll
    for (int i = 0; i < 4; ++i)
        #pragma unroll
        for (int j = 0; j < 4; ++j)
            acc[i][j] = (f32x4){0.f, 0.f, 0.f, 0.f};

    for (int k0 = 0; k0 < M_; k0 += 64) {
        __syncthreads();
        #pragma unroll
        for (int it = 0; it < 4; ++it) {
            int idx = it*256 + tid;
            int row = idx >> 3, seg = idx & 7;
            GLD(PhiQ + ((size_t)bh*N_ + nblk*128 + row)*M_ + k0 + seg*8, &sA[idx*8]);
            GLD(KVb  + ((size_t)bh*KVROWS_ + row)*M_ + k0 + seg*8, &sW[idx*8]);
        }
        __syncthreads();
        #pragma unroll
        for (int kk = 0; kk < 64; kk += 32) {
            bf16x8 af[4], wf[4];
            #pragma unroll
            for (int i = 0; i < 4; ++i)
                af[i] = *(const bf16x8*)&sA[(wm + i*16 + m16)*64 + kk + quad*8];
            #pragma unroll
            for (int j = 0; j < 4; ++j)
                wf[j] = *(const bf16x8*)&sW[(wn + j*16 + m16)*64 + kk + quad*8];
            #pragma unroll
            for (int i = 0; i < 4; ++i)
                #pragma unroll
                for (int j = 0; j < 4; ++j)
                    acc[i][j] = __builtin_amdgcn_mfma_f32_16x16x32_bf16(
                        af[i], wf[j], acc[i][j], 0, 0, 0);
        }
    }

    if (wn == 64 && m16 < 2) {
        #pragma unroll
        for (int i = 0; i < 4; ++i)
            #pragma unroll
            for (int r = 0; r < 4; ++r)
                sden[m16][wm + i*16 + quad*4 + r] = acc[i][0][r];
    }
    __syncthreads();
    if (wn == 0) {
        #pragma unroll
        for (int i = 0; i < 4; ++i) {
            int lrow0 = wm + i*16 + quad*4;
            #pragma unroll
            for (int r = 0; r < 4; ++r) {
                int lrow = lrow0 + r;
                int n = nblk*128 + lrow;
                float den = sden[0][lrow] + sden[1][lrow] + EPS_;
                #pragma unroll
                for (int j = 0; j < 4; ++j)
                    ctx[(size_t)(b*N_ + n)*D_ + h*DK_ + j*16 + m16] =
                        (bf16)(acc[i][j][r] / den);
            }
        }
    }
}

// ---------------------------------------------------------------------------
// Output projection: out = mask ? 0 : ctx @ Wout^T + bout   (bf16 MFMA, fp32 out)
// ---------------------------------------------------------------------------
__global__ __launch_bounds__(256)
void gemm_out(const bf16* __restrict__ A, const bf16* __restrict__ W,
              const float* __restrict__ bias, float* __restrict__ C,
              const int* __restrict__ mask)
{
    __shared__ bf16 sA[128*64];
    __shared__ bf16 sB[128*64];
    const int tid  = threadIdx.x;
    const int bm   = blockIdx.y * 128;
    const int bn   = blockIdx.x * 128;
    const int lane = tid & 63, wave = tid >> 6;
    const int wm   = (wave & 1) * 64, wn = (wave >> 1) * 64;
    const int m16  = lane & 15, quad = lane >> 4;

    f32x4 acc[4][4];
    #pragma unroll
    for (int i = 0; i < 4; ++i)
        #pragma unroll
        for (int j = 0; j < 4; ++j)
            acc[i][j] = (f32x4){0.f, 0.f, 0.f, 0.f};

    for (int k0 = 0; k0 < D_; k0 += 64) {
        __syncthreads();
        #pragma unroll
        for (int it = 0; it < 4; ++it) {
            int idx = it*256 + tid;
            int row = idx >> 3, seg = idx & 7;
            GLD(A + (size_t)(bm + row) * D_ + k0 + seg*8, &sA[idx*8]);
            GLD(W + (size_t)(bn + row) * D_ + k0 + seg*8, &sB[idx*8]);
        }
        __syncthreads();
        #pragma unroll
        for (int kk = 0; kk < 64; kk += 32) {
            bf16x8 af[4], bfr[4];
            #pragma unroll
            for (int i = 0; i < 4; ++i)
                af[i] = *(const bf16x8*)&sA[(wm + i*16 + m16)*64 + kk + quad*8];
            #pragma unroll
            for (int j = 0; j < 4; ++j)
                bfr[j] = *(const bf16x8*)&sB[(wn + j*16 + m16)*64 + kk + quad*8];
            #pragma unroll
            for (int i = 0; i < 4; ++i)
                #pragma unroll
                for (int j = 0; j < 4; ++j)
                    acc[i][j] = __builtin_amdgcn_mfma_f32_16x16x32_bf16(
                        af[i], bfr[j], acc[i][j], 0, 0, 0);
        }
    }

    #pragma unroll
    for (int j = 0; j < 4; ++j) {
        int col = bn + wn + j*16 + m16;
        float bv = bias[col];
        #pragma unroll
        for (int i = 0; i < 4; ++i) {
            int row0 = bm + wm + i*16 + quad*4;
            #pragma unroll
            for (int r = 0; r < 4; ++r) {
                int row = row0 + r;
                float v = acc[i][j][r] + bv;
                if (mask[row] != 0) v = 0.0f;
                C[(size_t)row * D_ + col] = v;
            }
        }
    }
}

// ---------------------------------------------------------------------------
extern "C" void kernel_launch(void* const* d_in, const int* in_sizes, int n_in,
                              void* d_out, int out_size, void* d_ws, size_t ws_size,
                              hipStream_t stream)
{
    const float* x     = (const float*)d_in[0];
    const int*   mask  = (const int*)d_in[1];     // 1 = PAD
    const float* Wqkv  = (const float*)d_in[2];
    const float* bqkv  = (const float*)d_in[3];
    const float* Wout  = (const float*)d_in[4];
    const float* bout  = (const float*)d_in[5];
    const float* omega = (const float*)d_in[6];
    float* out = (float*)d_out;

    // Workspace: 262.1 MB (ws_size = 256 MiB = 268.4 MB; round-4 used exactly it).
    // PH is the FULL 134.2 MB Phi buffer (B*H*N*M bf16 = 4x the Q size --
    // round 5's fatal bug aliased it onto 33.5 MB). xh overlaps PH's base:
    // xh dead after gemm_qkv (step 1); PH first written at step 2.
    char* w = (char*)d_ws;
    f16*   Wh    = (f16*)w;    w += (size_t)3*D_*D_ * 2;              //   6.29 MB
    bf16*  Wob   = (bf16*)w;   w += (size_t)D_*D_ * 2;                //   2.10 MB
    f16*   omhi  = (f16*)w;    w += (size_t)H_*M_*DK_ * 2;            //   0.52 MB
    f16*   omlo  = (f16*)w;    w += (size_t)H_*M_*DK_ * 2;            //   0.52 MB
    bf16*  PH    = (bf16*)w;   w += (size_t)B_*H_*N_*M_ * 2;          // 134.22 MB
    f16*   Qh    = (f16*)w;    w += (size_t)R_ * D_ * 2;              //  33.55 MB
    f16*   Kh    = (f16*)w;    w += (size_t)R_ * D_ * 2;              //  33.55 MB (-> ctx)
    bf16*  VT    = (bf16*)w;   w += (size_t)B_*H_*VTROWS_*N_ * 2;     //  41.94 MB
    float* KVt32 = (float*)w;  w += (size_t)B_*H_*VTROWS_*M_ * 4;     //   5.24 MB
    bf16*  KVb   = (bf16*)w;   w += (size_t)B_*H_*KVROWS_*M_ * 2;     //   4.19 MB
    f16*   xh    = (f16*)PH;                                          // alias (dead after step 1)
    bf16*  VC    = (bf16*)Kh;                                         // alias (Kh dead after step 2)

    // 0) prep
    split_f16<<<(R_*D_ + 255)/256, 256, 0, stream>>>(x, xh, nullptr, R_*D_);
    split_f16<<<(3*D_*D_ + 255)/256, 256, 0, stream>>>(Wqkv, Wh, nullptr, 3*D_*D_);
    split_f16<<<(H_*M_*DK_ + 255)/256, 256, 0, stream>>>(omega, omhi, omlo, H_*M_*DK_);
    f32_to_bf16<<<(D_*D_ + 255)/256, 256, 0, stream>>>(Wout, Wob, D_*D_);
    zero_f32<<<(B_*H_*VTROWS_*M_ + 255)/256, 256, 0, stream>>>(KVt32, B_*H_*VTROWS_*M_);
    init_vt<<<(B_*H_*16*N_ + 255)/256, 256, 0, stream>>>(VT);

    // 1) unified QKV projection (fp16): Qh, Kh fp16; V -> VT bf16 transposed
    gemm_qkv<<<dim3(3*D_/128, R_/128), 256, 0, stream>>>(xh, Wh, bqkv, Qh, Kh, VT);

    // 2) K features -> PhiT (masked) -- overwrites xh region (dead)
    feat_kernel<1><<<dim3(N_/128, H_, B_), 256, 0, stream>>>(Kh, omhi, omlo, mask, PH);

    // 3) KV + ksum: PhiT x VT -> KVt32 (atomics)
    kv_gemm<<<dim3(4, H_, B_), 256, 0, stream>>>(PH, VT, KVt32);

    // 4) pack KVt32 -> KVb bf16 (ksum hi/lo rows 64/65, zero pad to 128)
    pack_kv<<<(B_*H_*KVROWS_*M_ + 255)/256, 256, 0, stream>>>(KVt32, KVb);

    // 5) Q features -> PhiQ (reuses PH; PhiT dead after kv_gemm)
    feat_kernel<0><<<dim3(N_/128, H_, B_), 256, 0, stream>>>(Qh, omhi, omlo, mask, PH);

    // 6) ctx = num/den -> VC bf16 (aliases Kh; Kh dead after feat-K)
    ctx_gemm<<<dim3(N_/128, H_, B_), 256, 0, stream>>>(PH, KVb, VC);

    // 7) output projection + bias + PAD-query zeroing -> fp32 out
    gemm_out<<<dim3(8, R_/128), 256, 0, stream>>>(VC, Wob, bout, out, mask);
}

// Round 7
// 619.469 us; speedup vs baseline: 3.3978x; 1.0706x over previous
//
#include <hip/hip_runtime.h>
#include <hip/hip_bf16.h>
#include <math.h>

#define B_  4
#define N_  4096
#define D_  1024
#define H_  16
#define DK_ 64
#define M_  256
#define R_  (B_*N_)          // 16384 rows
#define EPS_ 1e-6f
#define VTROWS_ 80           // 64 V rows + row64=ones(ksum) + 65..79 pad
#define KVROWS_ 128          // KVb bf16: 64 KV + 64=ksum_hi + 65=ksum_lo + 0-pad
#define PHK_PAD 136          // fused_kv  Phi LDS [m][136]
#define PHQ_PAD 264          // fused_ctx Phi LDS [n][264]

typedef __bf16 bf16;
typedef __bf16 bf16x4 __attribute__((ext_vector_type(4)));
typedef __bf16 bf16x8 __attribute__((ext_vector_type(8)));
typedef _Float16 f16;
typedef _Float16 f16x4 __attribute__((ext_vector_type(4)));
typedef _Float16 f16x8 __attribute__((ext_vector_type(8)));
typedef float  f32x4  __attribute__((ext_vector_type(4)));

#define GLD(gp, lp) __builtin_amdgcn_global_load_lds( \
    (const __attribute__((address_space(1))) void*)(gp), \
    (__attribute__((address_space(3))) void*)(lp), 16, 0, 0)

// ---------------------------------------------------------------------------
// prep kernels
// ---------------------------------------------------------------------------
// fp32 -> f16 hi (+ optional lo residual), vectorized x4 (n % 4 == 0)
__global__ __launch_bounds__(256)
void split_f16v(const float* __restrict__ in, f16* __restrict__ hi,
                f16* __restrict__ lo, int n4)
{
    int i = blockIdx.x * 256 + threadIdx.x;
    if (i < n4) {
        float4 v = ((const float4*)in)[i];
        f16x4 h = { (f16)v.x, (f16)v.y, (f16)v.z, (f16)v.w };
        ((f16x4*)hi)[i] = h;
        if (lo) {
            f16x4 l = { (f16)(v.x - (float)h[0]), (f16)(v.y - (float)h[1]),
                        (f16)(v.z - (float)h[2]), (f16)(v.w - (float)h[3]) };
            ((f16x4*)lo)[i] = l;
        }
    }
}

__global__ __launch_bounds__(256)
void f32_to_bf16v(const float* __restrict__ in, bf16* __restrict__ o, int n4)
{
    int i = blockIdx.x * 256 + threadIdx.x;
    if (i < n4) {
        float4 v = ((const float4*)in)[i];
        bf16x4 h = { (bf16)v.x, (bf16)v.y, (bf16)v.z, (bf16)v.w };
        ((bf16x4*)o)[i] = h;
    }
}

__global__ __launch_bounds__(256)
void zero_f32(float* __restrict__ p, int n)
{
    int i = blockIdx.x * 256 + threadIdx.x;
    if (i < n) p[i] = 0.f;
}

// init VT rows 64..79: row 64 = 1.0 (ksum ones-row), rows 65..79 = 0
__global__ __launch_bounds__(256)
void init_vt(bf16* __restrict__ VT)
{
    int i = blockIdx.x * 256 + threadIdx.x;          // 64bh x 16rows x 4096
    if (i >= B_*H_*16*N_) return;
    int bh  = i >> 16;
    int rem = i & 65535;
    int row = 64 + (rem >> 12);
    int n   = rem & (N_-1);
    VT[((size_t)bh*VTROWS_ + row)*N_ + n] = (row == 64) ? (bf16)1.0f : (bf16)0.0f;
}

// KVt32 (80 rows: 64 KV + ksum row) -> KVb bf16 (128 rows: KV, ksum_hi, ksum_lo, 0)
__global__ __launch_bounds__(256)
void pack_kv(const float* __restrict__ KVt32, bf16* __restrict__ KVb)
{
    int i = blockIdx.x * 256 + threadIdx.x;          // 64bh x 128 x 256
    if (i >= B_*H_*KVROWS_*M_) return;
    int bh  = i >> 15;
    int rem = i & 32767;
    int row = rem >> 8;
    int m   = rem & (M_-1);
    bf16 o = (bf16)0.0f;
    if (row < 64) {
        o = (bf16)KVt32[((size_t)bh*VTROWS_ + row)*M_ + m];
    } else if (row == 64) {
        o = (bf16)KVt32[((size_t)bh*VTROWS_ + 64)*M_ + m];
    } else if (row == 65) {
        float v = KVt32[((size_t)bh*VTROWS_ + 64)*M_ + m];
        o = (bf16)(v - (float)(bf16)v);
    }
    KVb[i] = o;
}

// ---------------------------------------------------------------------------
// Unified QKV projection, single-pass fp16 MFMA (unchanged from round 6).
// ---------------------------------------------------------------------------
__global__ __launch_bounds__(256)
void gemm_qkv(const f16* __restrict__ X, const f16* __restrict__ Wh,
              const float* __restrict__ bqkv,
              f16* __restrict__ Qh, f16* __restrict__ Kh, bf16* __restrict__ VT)
{
    __shared__ f16 sA[128*64];        // 16 KB
    __shared__ f16 sB[128*64];        // 16 KB
    const int tid  = threadIdx.x;
    const int bm   = blockIdx.y * 128;
    const int bn   = blockIdx.x * 128;
    const int lane = tid & 63, wave = tid >> 6;
    const int wm   = (wave & 1) * 64, wn = (wave >> 1) * 64;
    const int m16  = lane & 15, quad = lane >> 4;

    f32x4 acc[4][4];
    #pragma unroll
    for (int i = 0; i < 4; ++i)
        #pragma unroll
        for (int j = 0; j < 4; ++j)
            acc[i][j] = (f32x4){0.f, 0.f, 0.f, 0.f};

    for (int k0 = 0; k0 < D_; k0 += 64) {
        __syncthreads();
        #pragma unroll
        for (int it = 0; it < 4; ++it) {
            int idx = it*256 + tid;
            int row = idx >> 3, seg = idx & 7;
            GLD(X  + (size_t)(bm + row) * D_ + k0 + seg*8, &sA[idx*8]);
            GLD(Wh + (size_t)(bn + row) * D_ + k0 + seg*8, &sB[idx*8]);
        }
        __syncthreads();
        #pragma unroll
        for (int kk = 0; kk < 64; kk += 32) {
            f16x8 af[4], bfr[4];
            #pragma unroll
            for (int i = 0; i < 4; ++i)
                af[i] = *(const f16x8*)&sA[(wm + i*16 + m16)*64 + kk + quad*8];
            #pragma unroll
            for (int j = 0; j < 4; ++j)
                bfr[j] = *(const f16x8*)&sB[(wn + j*16 + m16)*64 + kk + quad*8];
            #pragma unroll
            for (int i = 0; i < 4; ++i)
                #pragma unroll
                for (int j = 0; j < 4; ++j)
                    acc[i][j] = __builtin_amdgcn_mfma_f32_16x16x32_f16(
                        af[i], bfr[j], acc[i][j], 0, 0, 0);
        }
    }

    #pragma unroll
    for (int j = 0; j < 4; ++j) {
        int gcol = bn + wn + j*16 + m16;
        float bv = bqkv[gcol];
        #pragma unroll
        for (int i = 0; i < 4; ++i) {
            int row0 = bm + wm + i*16 + quad*4;
            if (gcol >= 2*D_) {
                int vcol = gcol - 2*D_;
                int hh = vcol >> 6, dd = vcol & 63;
                int bb = row0 >> 12, nn = row0 & (N_-1);
                bf16x4 pk = { (bf16)(acc[i][j][0]+bv), (bf16)(acc[i][j][1]+bv),
                              (bf16)(acc[i][j][2]+bv), (bf16)(acc[i][j][3]+bv) };
                *(bf16x4*)&VT[(((size_t)bb*H_+hh)*VTROWS_ + dd)*N_ + nn] = pk;
            } else if (gcol >= D_) {
                #pragma unroll
                for (int r = 0; r < 4; ++r)
                    Kh[(size_t)(row0+r) * D_ + gcol - D_] = (f16)(acc[i][j][r] + bv);
            } else {
                #pragma unroll
                for (int r = 0; r < 4; ++r)
                    Qh[(size_t)(row0+r) * D_ + gcol] = (f16)(acc[i][j][r] + bv);
            }
        }
    }
}

// ---------------------------------------------------------------------------
// fused_kv: per (b,h, n-slab of 1024): for each 128-key sub-tile:
//   feat (fp16 MFMA, omega hi/lo) -> rowmax -> exp -> Phi bf16 into LDS [m][n]
//   (padded 136, PAD keys zeroed), then KVt[d][m] += sum_n VT[d][n]*Phi[m][n]
//   via MFMA against LDS VT slab.  PhiT never touches HBM.
// Atomic-accumulate KVt32 (80 x 256 fp32, row 64 = ksum via VT ones-row).
// ---------------------------------------------------------------------------
__global__ __launch_bounds__(256)
void fused_kv(const f16* __restrict__ Kh, const bf16* __restrict__ VT,
              const f16* __restrict__ omhi, const f16* __restrict__ omlo,
              const int* __restrict__ mask, float* __restrict__ KVt32)
{
    __shared__ f16  sK[128*64];          // 16 KB
    __shared__ bf16 sVT[VTROWS_*128];    // 20 KB
    __shared__ bf16 sPhi[M_*PHK_PAD];    // 68 KB  [m][n] pad 136
    __shared__ int  sMask[128];
    const int nsp = blockIdx.x;          // 0..3
    const int h = blockIdx.y, b = blockIdx.z;
    const int bh = b*H_ + h;
    const int tid = threadIdx.x, lane = tid & 63, wave = tid >> 6;
    const int m16 = lane & 15, quad = lane >> 4;
    const int wm = wave * 64;            // wave's m-range for kv MFMA
    const float inv_sqrt_m = rsqrtf((float)M_ + 1e-6f);
    const f16* omh = omhi + (size_t)h * M_ * DK_;
    const f16* oml = omlo + (size_t)h * M_ * DK_;

    f32x4 kvacc[5][4];
    #pragma unroll
    for (int d = 0; d < 5; ++d)
        #pragma unroll
        for (int j = 0; j < 4; ++j)
            kvacc[d][j] = (f32x4){0.f, 0.f, 0.f, 0.f};

    for (int sub = 0; sub < 8; ++sub) {
        const int n0 = nsp*1024 + sub*128;
        __syncthreads();   // prior iter's readers of sK/sVT/sMask are done
        #pragma unroll
        for (int it = 0; it < 4; ++it) {   // K slab 128x64 f16
            int idx = it*256 + tid;
            int row = idx >> 3, seg = idx & 7;
            GLD(Kh + (size_t)(b*N_ + n0 + row) * D_ + h*DK_ + seg*8, &sK[idx*8]);
        }
        #pragma unroll
        for (int it = 0; it < 5; ++it) {   // VT slab 80x128 bf16 (1280 segs)
            int idx = it*256 + tid;
            int row = idx >> 4, seg = idx & 15;
            GLD(VT + ((size_t)bh*VTROWS_ + row)*N_ + n0 + seg*8, &sVT[idx*8]);
        }
        if (tid < 128) sMask[tid] = mask[b*N_ + n0 + tid];
        __syncthreads();

        // ---- feat: proj = K . omega^T (wave owns 32 n-rows) ----
        f16x8 ah[2][2];
        #pragma unroll
        for (int i = 0; i < 2; ++i)
            #pragma unroll
            for (int k = 0; k < 2; ++k)
                ah[i][k] = *(const f16x8*)&sK[(wave*32 + i*16 + m16)*64 + k*32 + quad*8];

        f32x4 acc[2][16];
        #pragma unroll
        for (int i = 0; i < 2; ++i)
            #pragma unroll
            for (int j = 0; j < 16; ++j)
                acc[i][j] = (f32x4){0.f, 0.f, 0.f, 0.f};

        #pragma unroll
        for (int j = 0; j < 16; ++j) {
            size_t ro = (size_t)(j*16 + m16) * DK_ + quad*8;
            f16x8 bh0 = *(const f16x8*)&omh[ro];
            f16x8 bh1 = *(const f16x8*)&omh[ro + 32];
            f16x8 bl0 = *(const f16x8*)&oml[ro];
            f16x8 bl1 = *(const f16x8*)&oml[ro + 32];
            #pragma unroll
            for (int i = 0; i < 2; ++i) {
                acc[i][j] = __builtin_amdgcn_mfma_f32_16x16x32_f16(ah[i][0], bh0, acc[i][j], 0,0,0);
                acc[i][j] = __builtin_amdgcn_mfma_f32_16x16x32_f16(ah[i][0], bl0, acc[i][j], 0,0,0);
                acc[i][j] = __builtin_amdgcn_mfma_f32_16x16x32_f16(ah[i][1], bh1, acc[i][j], 0,0,0);
                acc[i][j] = __builtin_amdgcn_mfma_f32_16x16x32_f16(ah[i][1], bl1, acc[i][j], 0,0,0);
            }
        }
        // rowmax + exp
        #pragma unroll
        for (int i = 0; i < 2; ++i)
            #pragma unroll
            for (int r = 0; r < 4; ++r) {
                float mx = acc[i][0][r];
                #pragma unroll
                for (int j = 1; j < 16; ++j) mx = fmaxf(mx, acc[i][j][r]);
                mx = fmaxf(mx, __shfl_xor(mx, 1, 64));
                mx = fmaxf(mx, __shfl_xor(mx, 2, 64));
                mx = fmaxf(mx, __shfl_xor(mx, 4, 64));
                mx = fmaxf(mx, __shfl_xor(mx, 8, 64));
                #pragma unroll
                for (int j = 0; j < 16; ++j)
                    acc[i][j][r] = __expf(acc[i][j][r] - mx) * inv_sqrt_m;
            }
        // Phi -> LDS [m][n] padded, PAD keys zeroed (bf16x4 along n)
        #pragma unroll
        for (int i = 0; i < 2; ++i) {
            int nloc = wave*32 + i*16 + quad*4;
            #pragma unroll
            for (int j = 0; j < 16; ++j) {
                bf16x4 pk;
                #pragma unroll
                for (int r = 0; r < 4; ++r)
                    pk[r] = sMask[nloc + r] ? (bf16)0.0f : (bf16)acc[i][j][r];
                *(bf16x4*)&sPhi[(j*16 + m16)*PHK_PAD + nloc] = pk;
            }
        }
        __syncthreads();

        // ---- kv MFMA: KVt[d][m] += sum_n VT[d][n] * Phi[m][n] ----
        #pragma unroll
        for (int kk = 0; kk < 128; kk += 32) {
            bf16x8 av[5], bp[4];
            #pragma unroll
            for (int d = 0; d < 5; ++d)
                av[d] = *(const bf16x8*)&sVT[(d*16 + m16)*128 + kk + quad*8];
            #pragma unroll
            for (int j = 0; j < 4; ++j)
                bp[j] = *(const bf16x8*)&sPhi[(wm + j*16 + m16)*PHK_PAD + kk + quad*8];
            #pragma unroll
            for (int d = 0; d < 5; ++d)
                #pragma unroll
                for (int j = 0; j < 4; ++j)
                    kvacc[d][j] = __builtin_amdgcn_mfma_f32_16x16x32_bf16(
                        av[d], bp[j], kvacc[d][j], 0, 0, 0);
        }
    }

    #pragma unroll
    for (int d = 0; d < 5; ++d)
        #pragma unroll
        for (int j = 0; j < 4; ++j) {
            int drow = d*16 + quad*4;
            int m = wm + j*16 + m16;
            #pragma unroll
            for (int r = 0; r < 4; ++r)
                atomicAdd(&KVt32[((size_t)bh*VTROWS_ + drow + r)*M_ + m],
                          kvacc[d][j][r]);
        }
}

// ---------------------------------------------------------------------------
// fused_ctx: per (b,h, 128 q-rows): feat -> exp -> Phi bf16 into LDS [n][m]
// (padded 264), then ctx = (Phi @ KVb^T)/den with KVb staged per k0.
// num cols 0..63, den = col64+col65+EPS.  PhiQ never touches HBM.
// ---------------------------------------------------------------------------
__global__ __launch_bounds__(256)
void fused_ctx(const f16* __restrict__ Qh, const f16* __restrict__ omhi,
               const f16* __restrict__ omlo, const bf16* __restrict__ KVb,
               bf16* __restrict__ ctx)
{
    __shared__ f16  sQ[128*64];          // 16 KB
    __shared__ bf16 sW[128*64];          // 16 KB
    __shared__ bf16 sPhi[128*PHQ_PAD];   // 67.6 KB [n][m] pad 264
    __shared__ float sden[2][128];
    const int nblk = blockIdx.x, h = blockIdx.y, b = blockIdx.z;
    const int bh = b*H_ + h;
    const int tid = threadIdx.x, lane = tid & 63, wave = tid >> 6;
    const int m16 = lane & 15, quad = lane >> 4;
    const float inv_sqrt_m = rsqrtf((float)M_ + 1e-6f);
    const f16* omh = omhi + (size_t)h * M_ * DK_;
    const f16* oml = omlo + (size_t)h * M_ * DK_;

    #pragma unroll
    for (int it = 0; it < 4; ++it) {     // Q slab 128x64 f16
        int idx = it*256 + tid;
        int row = idx >> 3, seg = idx & 7;
        GLD(Qh + (size_t)(b*N_ + nblk*128 + row) * D_ + h*DK_ + seg*8, &sQ[idx*8]);
    }
    __syncthreads();

    // ---- feat (wave owns 32 n-rows) ----
    {
        f16x8 ah[2][2];
        #pragma unroll
        for (int i = 0; i < 2; ++i)
            #pragma unroll
            for (int k = 0; k < 2; ++k)
                ah[i][k] = *(const f16x8*)&sQ[(wave*32 + i*16 + m16)*64 + k*32 + quad*8];

        f32x4 acc[2][16];
        #pragma unroll
        for (int i = 0; i < 2; ++i)
            #pragma unroll
            for (int j = 0; j < 16; ++j)
                acc[i][j] = (f32x4){0.f, 0.f, 0.f, 0.f};

        #pragma unroll
        for (int j = 0; j < 16; ++j) {
            size_t ro = (size_t)(j*16 + m16) * DK_ + quad*8;
            f16x8 bh0 = *(const f16x8*)&omh[ro];
            f16x8 bh1 = *(const f16x8*)&omh[ro + 32];
            f16x8 bl0 = *(const f16x8*)&oml[ro];
            f16x8 bl1 = *(const f16x8*)&oml[ro + 32];
            #pragma unroll
            for (int i = 0; i < 2; ++i) {
                acc[i][j] = __builtin_amdgcn_mfma_f32_16x16x32_f16(ah[i][0], bh0, acc[i][j], 0,0,0);
                acc[i][j] = __builtin_amdgcn_mfma_f32_16x16x32_f16(ah[i][0], bl0, acc[i][j], 0,0,0);
                acc[i][j] = __builtin_amdgcn_mfma_f32_16x16x32_f16(ah[i][1], bh1, acc[i][j], 0,0,0);
                acc[i][j] = __builtin_amdgcn_mfma_f32_16x16x32_f16(ah[i][1], bl1, acc[i][j], 0,0,0);
            }
        }
        #pragma unroll
        for (int i = 0; i < 2; ++i)
            #pragma unroll
            for (int r = 0; r < 4; ++r) {
                float mx = acc[i][0][r];
                #pragma unroll
                for (int j = 1; j < 16; ++j) mx = fmaxf(mx, acc[i][j][r]);
                mx = fmaxf(mx, __shfl_xor(mx, 1, 64));
                mx = fmaxf(mx, __shfl_xor(mx, 2, 64));
                mx = fmaxf(mx, __shfl_xor(mx, 4, 64));
                mx = fmaxf(mx, __shfl_xor(mx, 8, 64));
                #pragma unroll
                for (int j = 0; j < 16; ++j)
                    acc[i][j][r] = __expf(acc[i][j][r] - mx) * inv_sqrt_m;
            }
        // Phi -> LDS [n][m] padded (scalar b16; pad kills write conflicts)
        #pragma unroll
        for (int i = 0; i < 2; ++i) {
            int nloc0 = wave*32 + i*16 + quad*4;
            #pragma unroll
            for (int j = 0; j < 16; ++j)
                #pragma unroll
                for (int r = 0; r < 4; ++r)
                    sPhi[(nloc0 + r)*PHQ_PAD + j*16 + m16] = (bf16)acc[i][j][r];
        }
    }
    __syncthreads();   // Phi visible; sQ reads done (sW is separate anyway)

    // ---- ctx GEMM: A = Phi (LDS), W = KVb (staged per k0) ----
    const int wm = (wave & 1) * 64, wn = (wave >> 1) * 64;
    f32x4 cacc[4][4];
    #pragma unroll
    for (int i = 0; i < 4; ++i)
        #pragma unroll
        for (int j = 0; j < 4; ++j)
            cacc[i][j] = (f32x4){0.f, 0.f, 0.f, 0.f};

    for (int k0 = 0; k0 < M_; k0 += 64) {
        __syncthreads();
        #pragma unroll
        for (int it = 0; it < 4; ++it) {
            int idx = it*256 + tid;
            int row = idx >> 3, seg = idx & 7;
            GLD(KVb + ((size_t)bh*KVROWS_ + row)*M_ + k0 + seg*8, &sW[idx*8]);
        }
        __syncthreads();
        #pragma unroll
        for (int kk = 0; kk < 64; kk += 32) {
            bf16x8 af[4], wf[4];
            #pragma unroll
            for (int i = 0; i < 4; ++i)
                af[i] = *(const bf16x8*)&sPhi[(wm + i*16 + m16)*PHQ_PAD + k0 + kk + quad*8];
            #pragma unroll
            for (int j = 0; j < 4; ++j)
                wf[j] = *(const bf16x8*)&sW[(wn + j*16 + m16)*64 + kk + quad*8];
            #pragma unroll
            for (int i = 0; i < 4; ++i)
                #pragma unroll
                for (int j = 0; j < 4; ++j)
                    cacc[i][j] = __builtin_amdgcn_mfma_f32_16x16x32_bf16(
                        af[i], wf[j], cacc[i][j], 0, 0, 0);
        }
    }

    if (wn == 64 && m16 < 2) {
        #pragma unroll
        for (int i = 0; i < 4; ++i)
            #pragma unroll
            for (int r = 0; r < 4; ++r)
                sden[m16][wm + i*16 + quad*4 + r] = cacc[i][0][r];
    }
    __syncthreads();
    if (wn == 0) {
        #pragma unroll
        for (int i = 0; i < 4; ++i) {
            int lrow0 = wm + i*16 + quad*4;
            #pragma unroll
            for (int r = 0; r < 4; ++r) {
                int lrow = lrow0 + r;
                int n = nblk*128 + lrow;
                float den = sden[0][lrow] + sden[1][lrow] + EPS_;
                #pragma unroll
                for (int j = 0; j < 4; ++j)
                    ctx[(size_t)(b*N_ + n)*D_ + h*DK_ + j*16 + m16] =
                        (bf16)(cacc[i][j][r] / den);
            }
        }
    }
}

// ---------------------------------------------------------------------------
// Output projection: out = mask ? 0 : ctx @ Wout^T + bout   (bf16 MFMA, fp32 out)
// ---------------------------------------------------------------------------
__global__ __launch_bounds__(256)
void gemm_out(const bf16* __restrict__ A, const bf16* __restrict__ W,
              const float* __restrict__ bias, float* __restrict__ C,
              const int* __restrict__ mask)
{
    __shared__ bf16 sA[128*64];
    __shared__ bf16 sB[128*64];
    const int tid  = threadIdx.x;
    const int bm   = blockIdx.y * 128;
    const int bn   = blockIdx.x * 128;
    const int lane = tid & 63, wave = tid >> 6;
    const int wm   = (wave & 1) * 64, wn = (wave >> 1) * 64;
    const int m16  = lane & 15, quad = lane >> 4;

    f32x4 acc[4][4];
    #pragma unroll
    for (int i = 0; i < 4; ++i)
        #pragma unroll
        for (int j = 0; j < 4; ++j)
            acc[i][j] = (f32x4){0.f, 0.f, 0.f, 0.f};

    for (int k0 = 0; k0 < D_; k0 += 64) {
        __syncthreads();
        #pragma unroll
        for (int it = 0; it < 4; ++it) {
            int idx = it*256 + tid;
            int row = idx >> 3, seg = idx & 7;
            GLD(A + (size_t)(bm + row) * D_ + k0 + seg*8, &sA[idx*8]);
            GLD(W + (size_t)(bn + row) * D_ + k0 + seg*8, &sB[idx*8]);
        }
        __syncthreads();
        #pragma unroll
        for (int kk = 0; kk < 64; kk += 32) {
            bf16x8 af[4], bfr[4];
            #pragma unroll
            for (int i = 0; i < 4; ++i)
                af[i] = *(const bf16x8*)&sA[(wm + i*16 + m16)*64 + kk + quad*8];
            #pragma unroll
            for (int j = 0; j < 4; ++j)
                bfr[j] = *(const bf16x8*)&sB[(wn + j*16 + m16)*64 + kk + quad*8];
            #pragma unroll
            for (int i = 0; i < 4; ++i)
                #pragma unroll
                for (int j = 0; j < 4; ++j)
                    acc[i][j] = __builtin_amdgcn_mfma_f32_16x16x32_bf16(
                        af[i], bfr[j], acc[i][j], 0, 0, 0);
        }
    }

    #pragma unroll
    for (int j = 0; j < 4; ++j) {
        int col = bn + wn + j*16 + m16;
        float bv = bias[col];
        #pragma unroll
        for (int i = 0; i < 4; ++i) {
            int row0 = bm + wm + i*16 + quad*4;
            #pragma unroll
            for (int r = 0; r < 4; ++r) {
                int row = row0 + r;
                float v = acc[i][j][r] + bv;
                if (mask[row] != 0) v = 0.0f;
                C[(size_t)row * D_ + col] = v;
            }
        }
    }
}

// ---------------------------------------------------------------------------
extern "C" void kernel_launch(void* const* d_in, const int* in_sizes, int n_in,
                              void* d_out, int out_size, void* d_ws, size_t ws_size,
                              hipStream_t stream)
{
    const float* x     = (const float*)d_in[0];
    const int*   mask  = (const int*)d_in[1];     // 1 = PAD
    const float* Wqkv  = (const float*)d_in[2];
    const float* bqkv  = (const float*)d_in[3];
    const float* Wout  = (const float*)d_in[4];
    const float* bout  = (const float*)d_in[5];
    const float* omega = (const float*)d_in[6];
    float* out = (float*)d_out;

    // Workspace: ~161.6 MB (no global Phi buffer anymore -- it lives in LDS).
    char* w = (char*)d_ws;
    f16*   Wh    = (f16*)w;    w += (size_t)3*D_*D_ * 2;              //   6.29 MB
    bf16*  Wob   = (bf16*)w;   w += (size_t)D_*D_ * 2;                //   2.10 MB
    f16*   omhi  = (f16*)w;    w += (size_t)H_*M_*DK_ * 2;            //   0.52 MB
    f16*   omlo  = (f16*)w;    w += (size_t)H_*M_*DK_ * 2;            //   0.52 MB
    f16*   xh    = (f16*)w;    w += (size_t)R_ * D_ * 2;              //  33.55 MB
    f16*   Qh    = (f16*)w;    w += (size_t)R_ * D_ * 2;              //  33.55 MB
    f16*   Kh    = (f16*)w;    w += (size_t)R_ * D_ * 2;              //  33.55 MB (-> ctx)
    bf16*  VT    = (bf16*)w;   w += (size_t)B_*H_*VTROWS_*N_ * 2;     //  41.94 MB
    float* KVt32 = (float*)w;  w += (size_t)B_*H_*VTROWS_*M_ * 4;     //   5.24 MB
    bf16*  KVb   = (bf16*)w;   w += (size_t)B_*H_*KVROWS_*M_ * 2;     //   4.19 MB
    bf16*  VC    = (bf16*)Kh;                                         // alias (Kh dead after fused_kv)

    // 0) prep
    split_f16v<<<(R_*D_/4 + 255)/256, 256, 0, stream>>>(x, xh, nullptr, R_*D_/4);
    split_f16v<<<(3*D_*D_/4 + 255)/256, 256, 0, stream>>>(Wqkv, Wh, nullptr, 3*D_*D_/4);
    split_f16v<<<(H_*M_*DK_/4 + 255)/256, 256, 0, stream>>>(omega, omhi, omlo, H_*M_*DK_/4);
    f32_to_bf16v<<<(D_*D_/4 + 255)/256, 256, 0, stream>>>(Wout, Wob, D_*D_/4);
    zero_f32<<<(B_*H_*VTROWS_*M_ + 255)/256, 256, 0, stream>>>(KVt32, B_*H_*VTROWS_*M_);
    init_vt<<<(B_*H_*16*N_ + 255)/256, 256, 0, stream>>>(VT);

    // 1) unified QKV projection (fp16): Qh, Kh fp16; V -> VT bf16 transposed
    gemm_qkv<<<dim3(3*D_/128, R_/128), 256, 0, stream>>>(xh, Wh, bqkv, Qh, Kh, VT);

    // 2) fused K-features + KV/ksum accumulation (Phi_K in LDS only)
    fused_kv<<<dim3(4, H_, B_), 256, 0, stream>>>(Kh, VT, omhi, omlo, mask, KVt32);

    // 3) pack KVt32 -> KVb bf16 (ksum hi/lo rows 64/65, zero pad to 128)
    pack_kv<<<(B_*H_*KVROWS_*M_ + 255)/256, 256, 0, stream>>>(KVt32, KVb);

    // 4) fused Q-features + ctx (Phi_Q in LDS only) -> VC bf16 (aliases Kh)
    fused_ctx<<<dim3(N_/128, H_, B_), 256, 0, stream>>>(Qh, omhi, omlo, KVb, VC);

    // 5) output projection + bias + PAD-query zeroing -> fp32 out
    gemm_out<<<dim3(8, R_/128), 256, 0, stream>>>(VC, Wob, bout, out, mask);
}